// Round 10
// baseline (363.512 us; speedup 1.0000x reference)
//
#include <hip/hip_runtime.h>
#include <hip/hip_bf16.h>
#include <stdint.h>

typedef __hip_bfloat16 bf16;
typedef __attribute__((ext_vector_type(8))) short bf16x8;   // 8 bf16 = 4 VGPRs (MFMA A/B frag)
typedef __attribute__((ext_vector_type(4))) float f32x4;    // MFMA C/D frag

#define CC 1024
#define TT 2048
#define BB 4
#define BT 8192     // BB*TT
#define HH 16
#define NN 64       // head size

#define MFMA(a, b, c) __builtin_amdgcn_mfma_f32_16x16x32_bf16(a, b, c, 0, 0, 0)

// async global->LDS, 16B per lane. Direct addrspace casts (addrspacecast),
// NOT via uintptr_t (inttoptr of flat addr -> garbage LDS offset -> fault).
#define GLD(g, l) __builtin_amdgcn_global_load_lds( \
    (const __attribute__((address_space(1))) void*)(g), \
    (__attribute__((address_space(3))) void*)(l), 16, 0, 0)

__device__ __forceinline__ short f2bs(float f) {
    bf16 h = __float2bfloat16(f);
    return *reinterpret_cast<short*>(&h);
}
__device__ __forceinline__ float bs2f(short s) {
    bf16 h = *reinterpret_cast<bf16*>(&s);
    return __bfloat162float(h);
}

// Blocked-tile index, 256-row tiles (xvars, WrT/WkT/WvT): tile (m>>8,k>>6) is
// 16384 contiguous elems, internal [kg8][row256][col8] == the LDS image of
// gemm256 staging, so GLD sweeps are fully contiguous.
__device__ __forceinline__ size_t blk_idx(int m, int k, int ktiles) {
    return ((size_t)(m >> 8) * ktiles + (k >> 6)) * 16384
         + ((k >> 3) & 7) * 2048 + (m & 255) * 8 + (k & 7);
}

// Blocked-tile index, 128-row tiles (A2, WoT): tile (m>>7,k>>6) is 8192
// contiguous elems, internal [kg8][row128][col8] == gemm128b LDS image.
__device__ __forceinline__ size_t blk128_idx(int m, int k, int ktiles) {
    return ((size_t)(m >> 7) * ktiles + (k >> 6)) * 8192
         + ((k >> 3) & 7) * 1024 + (m & 127) * 8 + (k & 7);
}

// ---------------------------------------------------------------------------
// 128x128 MFMA GEMM core, BK=32 (m97 structure) — used by g_xvar (kiters=1).
// ---------------------------------------------------------------------------
template <typename EPI>
__device__ __forceinline__ void gemm128(short* As, short* Bs,
                                        const bf16* __restrict__ A, int lda,
                                        const bf16* __restrict__ Bt, int ldb,
                                        int kiters, int m0, int n0, EPI epi)
{
    const int tid = threadIdx.x;
    const int l   = tid & 63, wv = tid >> 6;
    const int wm  = wv >> 1, wn = wv & 1;
    const int q   = l >> 4, lr = l & 15;
    const int row = tid & 127, kg1 = tid >> 7;

    f32x4 acc[4][4] = {};

    const bf16* ga = A  + (size_t)(m0 + row) * lda + kg1 * 8;
    const bf16* gb = Bt + (size_t)(n0 + row) * ldb + kg1 * 8;
    short* la1 = As + tid * 8;
    short* la2 = As + (tid + 256) * 8;
    short* lb1 = Bs + tid * 8;
    short* lb2 = Bs + (tid + 256) * 8;

    for (int kb = 0; kb < kiters; ++kb) {
        __syncthreads();
        const bf16* gak = ga + kb * 32;
        const bf16* gbk = gb + kb * 32;
        GLD(gak,      la1);
        GLD(gak + 16, la2);
        GLD(gbk,      lb1);
        GLD(gbk + 16, lb2);
        __syncthreads();
        bf16x8 af[4], bfb[4];
#pragma unroll
        for (int mt = 0; mt < 4; ++mt)
            af[mt] = *(const bf16x8*)(As + (q * 128 + wm * 64 + mt * 16 + lr) * 8);
#pragma unroll
        for (int nt = 0; nt < 4; ++nt)
            bfb[nt] = *(const bf16x8*)(Bs + (q * 128 + wn * 64 + nt * 16 + lr) * 8);
#pragma unroll
        for (int mt = 0; mt < 4; ++mt)
#pragma unroll
            for (int nt = 0; nt < 4; ++nt)
                acc[mt][nt] = MFMA(af[mt], bfb[nt], acc[mt][nt]);
    }
#pragma unroll
    for (int mt = 0; mt < 4; ++mt)
#pragma unroll
        for (int nt = 0; nt < 4; ++nt)
#pragma unroll
            for (int rr = 0; rr < 4; ++rr)
                epi(m0 + wm * 64 + mt * 16 + q * 4 + rr,
                    n0 + wn * 64 + nt * 16 + lr, acc[mt][nt][rr]);
}

// ---------------------------------------------------------------------------
// 128x128 MFMA GEMM core, BK=64, 2-phase dbuf, LINEAR row-major inputs.
// R3 schedule (stage-early, one barrier/K-step). Used by g_lora.
// ---------------------------------------------------------------------------
template <typename EPI>
__device__ __forceinline__ void gemm128L(short* As, short* Bs,
                                         const bf16* __restrict__ A, int lda,
                                         const bf16* __restrict__ Bt, int ldb,
                                         int kiters, int m0, int n0, EPI epi)
{
    const int tid = threadIdx.x;
    const int l   = tid & 63, wv = tid >> 6;
    const int wm  = wv >> 1, wn = wv & 1;
    const int q   = l >> 4, lr = l & 15;
    const int row = tid & 127, kg1 = tid >> 7;

    f32x4 acc[4][4] = {};

    const bf16* ga = A  + (size_t)(m0 + row) * lda + kg1 * 8;
    const bf16* gb = Bt + (size_t)(n0 + row) * ldb + kg1 * 8;

    auto stage = [&](int kb, int u) {
        const bf16* gak = ga + kb * 64;
        const bf16* gbk = gb + kb * 64;
        short* la = As + u * 8192 + tid * 8;
        short* lb = Bs + u * 8192 + tid * 8;
        GLD(gak,      la);
        GLD(gak + 16, la + 2048);
        GLD(gak + 32, la + 4096);
        GLD(gak + 48, la + 6144);
        GLD(gbk,      lb);
        GLD(gbk + 16, lb + 2048);
        GLD(gbk + 32, lb + 4096);
        GLD(gbk + 48, lb + 6144);
    };

    __syncthreads();
    stage(0, 0);
    __syncthreads();
    for (int kb = 0; kb < kiters; ++kb) {
        const int cur = kb & 1;
        if (kb + 1 < kiters) stage(kb + 1, cur ^ 1);   // prefetch next K-tile
        const short* Ac = As + cur * 8192;
        const short* Bc = Bs + cur * 8192;
        bf16x8 af[2][4], bfb[2][4];
#pragma unroll
        for (int hh = 0; hh < 2; ++hh) {
#pragma unroll
            for (int mt = 0; mt < 4; ++mt)
                af[hh][mt] = *(const bf16x8*)(Ac +
                    ((q + hh * 4) * 128 + wm * 64 + mt * 16 + lr) * 8);
#pragma unroll
            for (int nt = 0; nt < 4; ++nt)
                bfb[hh][nt] = *(const bf16x8*)(Bc +
                    ((q + hh * 4) * 128 + wn * 64 + nt * 16 + lr) * 8);
        }
        __builtin_amdgcn_s_setprio(1);
#pragma unroll
        for (int mt = 0; mt < 4; ++mt)
#pragma unroll
            for (int nt = 0; nt < 4; ++nt) {
                acc[mt][nt] = MFMA(af[0][mt], bfb[0][nt], acc[mt][nt]);
                acc[mt][nt] = MFMA(af[1][mt], bfb[1][nt], acc[mt][nt]);
            }
        __builtin_amdgcn_s_setprio(0);
        __syncthreads();
    }
#pragma unroll
    for (int mt = 0; mt < 4; ++mt)
#pragma unroll
        for (int nt = 0; nt < 4; ++nt)
#pragma unroll
            for (int rr = 0; rr < 4; ++rr)
                epi(m0 + wm * 64 + mt * 16 + q * 4 + rr,
                    n0 + wn * 64 + nt * 16 + lr, acc[mt][nt][rr]);
}

// ---------------------------------------------------------------------------
// 128x128 MFMA GEMM core, BK=64, 2-phase dbuf, BLOCKED inputs (blk128_idx).
// R3 schedule. Used by g_out.
// ---------------------------------------------------------------------------
template <typename EPI>
__device__ __forceinline__ void gemm128b(short* As, short* Bs,
                                         const bf16* __restrict__ A,
                                         const bf16* __restrict__ Bt,
                                         int kiters, int m0, int n0, EPI epi)
{
    const int tid = threadIdx.x;
    const int l   = tid & 63, wv = tid >> 6;
    const int wm  = wv >> 1, wn = wv & 1;
    const int q   = l >> 4, lr = l & 15;

    f32x4 acc[4][4] = {};

    const bf16* ga = A  + (size_t)(m0 >> 7) * 16 * 8192 + tid * 8;
    const bf16* gb = Bt + (size_t)(n0 >> 7) * 16 * 8192 + tid * 8;

    auto stage = [&](int kb, int u) {
        const bf16* gak = ga + (size_t)kb * 8192;
        const bf16* gbk = gb + (size_t)kb * 8192;
        short* la = As + u * 8192 + tid * 8;
        short* lb = Bs + u * 8192 + tid * 8;
        GLD(gak,        la);
        GLD(gak + 2048, la + 2048);
        GLD(gak + 4096, la + 4096);
        GLD(gak + 6144, la + 6144);
        GLD(gbk,        lb);
        GLD(gbk + 2048, lb + 2048);
        GLD(gbk + 4096, lb + 4096);
        GLD(gbk + 6144, lb + 6144);
    };

    __syncthreads();
    stage(0, 0);
    __syncthreads();
    for (int kb = 0; kb < kiters; ++kb) {
        const int cur = kb & 1;
        if (kb + 1 < kiters) stage(kb + 1, cur ^ 1);   // prefetch next K-tile
        const short* Ac = As + cur * 8192;
        const short* Bc = Bs + cur * 8192;
        bf16x8 af[2][4], bfb[2][4];
#pragma unroll
        for (int hh = 0; hh < 2; ++hh) {
#pragma unroll
            for (int mt = 0; mt < 4; ++mt)
                af[hh][mt] = *(const bf16x8*)(Ac +
                    ((q + hh * 4) * 128 + wm * 64 + mt * 16 + lr) * 8);
#pragma unroll
            for (int nt = 0; nt < 4; ++nt)
                bfb[hh][nt] = *(const bf16x8*)(Bc +
                    ((q + hh * 4) * 128 + wn * 64 + nt * 16 + lr) * 8);
        }
        __builtin_amdgcn_s_setprio(1);
#pragma unroll
        for (int mt = 0; mt < 4; ++mt)
#pragma unroll
            for (int nt = 0; nt < 4; ++nt) {
                acc[mt][nt] = MFMA(af[0][mt], bfb[0][nt], acc[mt][nt]);
                acc[mt][nt] = MFMA(af[1][mt], bfb[1][nt], acc[mt][nt]);
            }
        __builtin_amdgcn_s_setprio(0);
        __syncthreads();
    }
#pragma unroll
    for (int mt = 0; mt < 4; ++mt)
#pragma unroll
        for (int nt = 0; nt < 4; ++nt)
#pragma unroll
            for (int rr = 0; rr < 4; ++rr)
                epi(m0 + wm * 64 + mt * 16 + q * 4 + rr,
                    n0 + wn * 64 + nt * 16 + lr, acc[mt][nt][rr]);
}

// ---------------------------------------------------------------------------
// 256x256 MFMA GEMM core, BK=64, 512 threads (8 waves, 2x4), 2-phase dbuf,
// R3 schedule (stage-early, one barrier/K-step) — proven optimum for this
// kernel (R4 counted-vmcnt and R8 8-phase both regressed). A and Bt BLOCKED
// (blk_idx). Output head-blocked via LDS-staged coalesced epilogue (R7).
// ---------------------------------------------------------------------------
__device__ __forceinline__ void gemm256(short* lds,
                                        const bf16* __restrict__ A,
                                        const bf16* __restrict__ Bt,
                                        int kiters, int m0, int n0,
                                        bf16* __restrict__ out)
{
    short* As = lds;
    short* Bs = lds + 32768;
    const int tid = threadIdx.x;            // 0..511
    const int l   = tid & 63, wv = tid >> 6;
    const int wm  = wv >> 2, wn = wv & 3;   // 2 x 4 wave grid
    const int q   = l >> 4, lr = l & 15;

    f32x4 acc[8][4] = {};

    const bf16* ga = A  + (size_t)(m0 >> 8) * 16 * 16384 + tid * 8;
    const bf16* gb = Bt + (size_t)(n0 >> 8) * 16 * 16384 + tid * 8;

    auto stage = [&](int kb, int u) {
        const bf16* gak = ga + (size_t)kb * 16384;
        const bf16* gbk = gb + (size_t)kb * 16384;
        short* la = As + u * 16384 + tid * 8;
        short* lb = Bs + u * 16384 + tid * 8;
        GLD(gak,         la);
        GLD(gak + 4096,  la + 4096);
        GLD(gak + 8192,  la + 8192);
        GLD(gak + 12288, la + 12288);
        GLD(gbk,         lb);
        GLD(gbk + 4096,  lb + 4096);
        GLD(gbk + 8192,  lb + 8192);
        GLD(gbk + 12288, lb + 12288);
    };

    __syncthreads();
    stage(0, 0);
    __syncthreads();
    for (int kb = 0; kb < kiters; ++kb) {
        const int cur = kb & 1;
        if (kb + 1 < kiters) stage(kb + 1, cur ^ 1);
        const short* Ac = As + cur * 16384;
        const short* Bc = Bs + cur * 16384;
#pragma unroll
        for (int hh = 0; hh < 2; ++hh) {    // per-k-half to bound VGPR
            bf16x8 af[8], bfb[4];
#pragma unroll
            for (int mt = 0; mt < 8; ++mt)
                af[mt] = *(const bf16x8*)(Ac +
                    ((q + hh * 4) * 256 + wm * 128 + mt * 16 + lr) * 8);
#pragma unroll
            for (int nt = 0; nt < 4; ++nt)
                bfb[nt] = *(const bf16x8*)(Bc +
                    ((q + hh * 4) * 256 + wn * 64 + nt * 16 + lr) * 8);
            __builtin_amdgcn_s_setprio(1);
#pragma unroll
            for (int mt = 0; mt < 8; ++mt)
#pragma unroll
                for (int nt = 0; nt < 4; ++nt)
                    acc[mt][nt] = MFMA(af[mt], bfb[nt], acc[mt][nt]);
            __builtin_amdgcn_s_setprio(0);
        }
        __syncthreads();
    }
    // ---- LDS-staged epilogue (dbuf LDS is dead; overlay [256][268] bf16) ----
    constexpr int EP = 268;                 // pad: q-groups hit disjoint banks
    short* E = lds;
#pragma unroll
    for (int mt = 0; mt < 8; ++mt)
#pragma unroll
        for (int nt = 0; nt < 4; ++nt)
#pragma unroll
            for (int rr = 0; rr < 4; ++rr) {
                int r    = wm * 128 + mt * 16 + q * 4 + rr;
                int ccol = wn * 64 + nt * 16 + lr;
                E[r * EP + ccol] = f2bs(acc[mt][nt][rr]);
            }
    __syncthreads();
    const int b     = m0 >> 11;             // batch
    const int hbase = n0 >> 6;              // first head of this n-tile
#pragma unroll
    for (int it = 0; it < 16; ++it) {
        int gidx = it * 512 + tid;          // 16-B units, 8192 total
        int hh   = gidx >> 11;              // head 0..3 (constant per wave)
        int u    = gidx & 2047;
        int r    = u >> 3;                  // row 0..255
        int cB   = (u & 7) * 8;             // col base (shorts)
        bf16x8 vdat = *(const bf16x8*)(E + r * EP + hh * 64 + cB);
        size_t o = (((size_t)(b * 16 + hbase + hh)) * 2048
                    + (size_t)((m0 & 2047) + r)) * 64 + cB;
        *(bf16x8*)((short*)out + o) = vdat;
    }
}

// ---------------------------------------------------------------------------
// 256x64 hidden-GEMM core (gate/decay), 512 threads, R3 schedule.
// A is BLOCKED (xvars layout); B = w1T2 slice stays linear (tiny traffic).
// ---------------------------------------------------------------------------
template <typename EPI>
__device__ __forceinline__ void gemmHid(short* As, short* Bs,
                                        const bf16* __restrict__ A,
                                        const bf16* __restrict__ Bt, int ldb,
                                        int kiters, int m0, EPI epi)
{
    const int tid = threadIdx.x;
    const int l   = tid & 63, wv = tid >> 6;    // wave -> 32-row slab
    const int q   = l >> 4, lr = l & 15;
    const int row64 = tid & 63, kg8 = tid >> 6; // B staging: 64 rows x 8 kgroups

    f32x4 acc[2][4] = {};

    const bf16* ga = A + (size_t)(m0 >> 8) * 16 * 16384 + tid * 8;
    const bf16* gb = Bt + (size_t)row64 * ldb + kg8 * 8;

    auto stage = [&](int kb, int u) {
        const bf16* gak = ga + (size_t)kb * 16384;
        short* la = As + u * 16384 + tid * 8;
        GLD(gak,         la);
        GLD(gak + 4096,  la + 4096);
        GLD(gak + 8192,  la + 8192);
        GLD(gak + 12288, la + 12288);
        GLD(gb + kb * 64, Bs + u * 4096 + tid * 8);
    };

    __syncthreads();
    stage(0, 0);
    __syncthreads();
    for (int kb = 0; kb < kiters; ++kb) {
        const int cur = kb & 1;
        if (kb + 1 < kiters) stage(kb + 1, cur ^ 1);
        const short* Ac = As + cur * 16384;
        const short* Bc = Bs + cur * 4096;
        bf16x8 af[2][2], bfb[2][4];
#pragma unroll
        for (int hh = 0; hh < 2; ++hh) {
#pragma unroll
            for (int mt = 0; mt < 2; ++mt)
                af[hh][mt] = *(const bf16x8*)(Ac +
                    ((q + hh * 4) * 256 + wv * 32 + mt * 16 + lr) * 8);
#pragma unroll
            for (int nt = 0; nt < 4; ++nt)
                bfb[hh][nt] = *(const bf16x8*)(Bc +
                    ((q + hh * 4) * 64 + nt * 16 + lr) * 8);
        }
#pragma unroll
        for (int mt = 0; mt < 2; ++mt)
#pragma unroll
            for (int nt = 0; nt < 4; ++nt) {
                acc[mt][nt] = MFMA(af[0][mt], bfb[0][nt], acc[mt][nt]);
                acc[mt][nt] = MFMA(af[1][mt], bfb[1][nt], acc[mt][nt]);
            }
        __syncthreads();
    }
#pragma unroll
    for (int mt = 0; mt < 2; ++mt)
#pragma unroll
        for (int nt = 0; nt < 4; ++nt)
#pragma unroll
            for (int rr = 0; rr < 4; ++rr)
                epi(m0 + wv * 32 + mt * 16 + q * 4 + rr,
                    nt * 16 + lr, acc[mt][nt][rr]);
}

// ---------------------------------------------------------------------------
// ALL prep in one launch: 13092 blocks (weights transpose + xxx/xb/xxb).
// WrT/WkT/WvT -> blk_idx layout; WoT -> blk128_idx layout; rest linear.
// ---------------------------------------------------------------------------
__global__ __launch_bounds__(256) void k_prep_all(
    const float* __restrict__ Wr, const float* __restrict__ Wk,
    const float* __restrict__ Wv, const float* __restrict__ Wo,
    const float* __restrict__ maa_w1, const float* __restrict__ gate_w1,
    const float* __restrict__ decay_w1, const float* __restrict__ gate_w2,
    const float* __restrict__ decay_w2, const float* __restrict__ maa_w2,
    const float* __restrict__ mw, const float* __restrict__ mk,
    const float* __restrict__ mv, const float* __restrict__ mr,
    const float* __restrict__ mg, const float* __restrict__ x,
    const float* __restrict__ maa_x,
    bf16* __restrict__ WT3, bf16* __restrict__ WoT, bf16* __restrict__ w1T,
    bf16* __restrict__ w1T2, bf16* __restrict__ w2T2, bf16* __restrict__ w2T5,
    float* __restrict__ maas, bf16* __restrict__ xxx,
    bf16* __restrict__ xb, bf16* __restrict__ xxb)
{
    __shared__ float tile[32][33];
    int idx = blockIdx.x;
    if (idx >= 4900) {                       // xb=x, xxb=shift(x)-x, xxx=x+xx*maa_x
        size_t i = ((size_t)(idx - 4900) * 256 + threadIdx.x) * 4;
        int cc = i & (CC - 1);
        int t  = (i >> 10) & (TT - 1);
        float4 xm = *(const float4*)(x + i);
        float4 xp = t ? *(const float4*)(x + i - CC)
                      : make_float4(0.f, 0.f, 0.f, 0.f);
        float4 ax = *(const float4*)(maa_x + cc);
        float xxv[4] = {xp.x - xm.x, xp.y - xm.y, xp.z - xm.z, xp.w - xm.w};
        float xmv[4] = {xm.x, xm.y, xm.z, xm.w};
        float axv[4] = {ax.x, ax.y, ax.z, ax.w};
#pragma unroll
        for (int e = 0; e < 4; ++e) {
            xb[i + e]  = __float2bfloat16(xmv[e]);
            xxb[i + e] = __float2bfloat16(xxv[e]);
            xxx[i + e] = __float2bfloat16(xmv[e] + xxv[e] * axv[e]);
        }
        return;
    }
    const float* src; bf16* dst; int rows, cols_in, tx_;
    int blkmode = 0;                         // 0=linear, 1=blk256, 2=blk128
    if (idx < 4096) {
        int s = idx >> 10; idx &= 1023;
        src = (s == 0) ? Wr : (s == 1) ? Wk : (s == 2) ? Wv : Wo;
        dst = (s == 3) ? WoT : WT3 + (size_t)s * CC * CC;
        blkmode = (s == 3) ? 2 : 1;
        rows = CC; cols_in = CC; tx_ = 32;
    } else if (idx < 4352) { idx -= 4096; src = maa_w1;  dst = w1T;  rows = CC; cols_in = 160; tx_ = 8; }
    else if (idx < 4480)   { idx -= 4352; src = gate_w1; dst = w1T2; rows = CC; cols_in = 64;  tx_ = 4; }
    else if (idx < 4608)   { idx -= 4480; src = decay_w1; dst = w1T2 + 128 * CC; rows = CC; cols_in = 64; tx_ = 4; }
    else if (idx < 4672)   { idx -= 4608; src = gate_w2;  dst = w2T2;           rows = 64; cols_in = CC; tx_ = 32; }
    else if (idx < 4736)   { idx -= 4672; src = decay_w2; dst = w2T2 + CC * 64; rows = 64; cols_in = CC; tx_ = 32; }
    else if (idx < 4896)   { idx -= 4736; int f = idx >> 5; idx &= 31;
                             src = maa_w2 + (size_t)f * 32 * CC;
                             dst = w2T5 + (size_t)f * CC * 32; rows = 32; cols_in = CC; tx_ = 32; }
    else {
        int i = (idx - 4896) * 256 + threadIdx.x;
        if (i < CC) {
            maas[i]          = mw[i];
            maas[CC + i]     = mk[i];
            maas[2 * CC + i] = mv[i];
            maas[3 * CC + i] = mr[i];
            maas[4 * CC + i] = mg[i];
        }
        return;
    }
    int bx = idx % tx_, by = idx / tx_;
    int c0 = bx * 32, r0 = by * 32;
    int tx = threadIdx.x & 31, ty = threadIdx.x >> 5;
    for (int i = ty; i < 32; i += 8) {
        int cc2 = c0 + tx;
        tile[i][tx] = (cc2 < cols_in) ? src[(size_t)(r0 + i) * cols_in + cc2] : 0.f;
    }
    __syncthreads();
    if (blkmode == 1) {
        for (int i = ty; i < 32; i += 8) {
            int R = c0 + i, C = r0 + tx;             // out row (n), k col
            dst[blk_idx(R, C, 16)] = __float2bfloat16(tile[tx][i]);
        }
    } else if (blkmode == 2) {
        for (int i = ty; i < 32; i += 8) {
            int R = c0 + i, C = r0 + tx;
            dst[blk128_idx(R, C, 16)] = __float2bfloat16(tile[tx][i]);
        }
    } else {
        for (int i = ty; i < 32; i += 8)
            dst[(size_t)(c0 + i) * rows + r0 + tx] = __float2bfloat16(tile[tx][i]);
    }
}

// g_lora: 2-phase BK=64 core (linear inputs). w1T rows 160..255 are zero-padded
// by prep, so the full 128-wide n-tile at n0=128 is safe; epi guards n<160.
__global__ __launch_bounds__(256) void g_lora(const bf16* __restrict__ xxx,
                                              const bf16* __restrict__ w1T,
                                              bf16* __restrict__ L)
{
    __shared__ __align__(16) short lds[32768];
    int m0 = blockIdx.x * 128, n0 = blockIdx.y * 128;
    gemm128L(lds, lds + 16384, xxx, CC, w1T, CC, CC / 64, m0, n0,
             [&](int m, int n, float v) {
                 if (n < 160) L[(size_t)m * 160 + n] = __float2bfloat16(tanhf(v));
             });
}

// All 5 xvars in one block; xvars written in BLOCKED layout (blk_idx).
__global__ __launch_bounds__(256) void g_xvar(const bf16* __restrict__ L,
                                              const bf16* __restrict__ w2T,
                                              const float* __restrict__ maas,
                                              const bf16* __restrict__ xb,
                                              const bf16* __restrict__ xxb,
                                              bf16* __restrict__ xvars)
{
    __shared__ __align__(16) short lds[8192];
    int m0 = blockIdx.x * 128, n0 = blockIdx.y * 128;
    for (int f = 0; f < 5; ++f) {
        const bf16* A  = L + f * 32;
        const bf16* Bt = w2T + (size_t)f * CC * 32;
        const float* maa = maas + f * CC;
        bf16* out = xvars + (size_t)f * BT * CC;
        gemm128(lds, lds + 4096, A, 160, Bt, 32, 1, m0, n0,
                [&](int m, int n, float v) {
                    float xm = __bfloat162float(xb[(size_t)m * CC + n]);
                    float xx = __bfloat162float(xxb[(size_t)m * CC + n]);
                    out[blk_idx(m, n, 16)] =
                        __float2bfloat16(xm + xx * (maa[n] + v));
                });
    }
}

// ---------------------------------------------------------------------------
// r/k/v GEMMs on the 256^2 core (blocks 0..383) + gate/decay hidden GEMMs on
// the 256x64 core (blocks 384..447, dispatched LAST to fill the tail round).
// Logical order: z outer, m middle, n FASTEST — consecutive 4 blocks on an
// XCD share the 512 KB A-panel (L2 hit after first touch) and the z's whole
// 2 MB B slice stays L2-resident across the chunk. (Old order was m-fastest:
// B-panel shared but A-panels only via contended L3 -> ~34 MB HBM re-fetch.)
// ---------------------------------------------------------------------------
__global__ __launch_bounds__(512) void g_rkv5(const bf16* __restrict__ xvars,
                                              const bf16* __restrict__ WT,
                                              const bf16* __restrict__ w1T2,
                                              bf16* __restrict__ rkv,
                                              bf16* __restrict__ hid)
{
    __shared__ __align__(16) short lds[68608];   // 134 KiB (epi needs 256x268)
    int bid = blockIdx.x;
    if (bid < 384) {
        int swz = (bid & 7) * 48 + (bid >> 3);   // 384 % 8 == 0: bijective
        int z  = swz >> 7;                       // 0=r,1=k,2=v
        int r2 = swz & 127;
        int m0 = (r2 >> 2) * 256;                // 32 m-tiles (middle)
        int n0 = (r2 & 3) * 256;                 // 4 n-tiles (fastest)
        int f = (z == 0) ? 3 : z;                // r<-xr(f3), k<-xk(f1), v<-xv(f2)
        const bf16* A  = xvars + (size_t)f * BT * CC;
        const bf16* Bt = WT + (size_t)z * CC * CC;
        bf16* out = rkv + (size_t)z * BT * CC;
        gemm256(lds, A, Bt, CC / 64, m0, n0, out);
    } else {
        int hb = bid - 384;
        int zz = hb >> 5, mi = hb & 31;          // 0=gate(f4), 1=decay(f0)
        const bf16* A  = xvars + (size_t)(zz == 0 ? 4 : 0) * BT * CC;
        const bf16* Bt = w1T2 + (size_t)zz * 128 * CC;
        bf16* out = hid + (size_t)zz * BT * 64;
        gemmHid(lds, lds + 32768, A, Bt, CC, CC / 64, mi * 256,
                [&](int m, int n, float v) {
                    out[(size_t)m * 64 + n] = __float2bfloat16(tanhf(v));
                });
    }
}

// ---------------------------------------------------------------------------
// Chunk-parallel WKV6, pass 1: grid 2048 = (bh,chunk), 256 thr / 4 waves.
// r/k/v and y in head-blocked [bh][t][64] layout (contiguous tiles).
// y written via LDS-staged coalesced epilogue (VT region reused).
// ---------------------------------------------------------------------------
__global__ __launch_bounds__(256) void k_wkv_p1(const bf16* __restrict__ r,
                                                const bf16* __restrict__ kk,
                                                const bf16* __restrict__ vv,
                                                const bf16* __restrict__ hidW,
                                                const bf16* __restrict__ w2d,
                                                const float* __restrict__ td,
                                                const float* __restrict__ u,
                                                bf16* __restrict__ y,
                                                bf16* __restrict__ RTg,
                                                short* __restrict__ Mg,
                                                float* __restrict__ plg)
{
    constexpr int PW = 65, PB = 72;
    __shared__ __align__(16) char smem[16640 + 3 * 9216 + 768];
    float* LW = (float*)smem;                          // [64][65] fp32 scan
    short* VT = (short*)smem;                          // [64][72] bf16 (overlay)
    short* RT = (short*)(smem + 16640);                // [64][72]
    short* KT = (short*)(smem + 16640 + 9216);         // [64][72]
    short* AT = KT;                                    // overlay after MFMA1
    short* KH = (short*)(smem + 16640 + 2 * 9216);     // [64][72]
    short* HT = KT;                                    // hid_w staging (pre-C)
    short* WD = KH;                                    // w2dec staging (pre-C)
    float* SU = (float*)(smem + 16640 + 3 * 9216);
    float* SD = SU + 64;

    const int tid = threadIdx.x;
    const int lane = tid & 63, wq = tid >> 6;
    const int row = tid >> 2, g = tid & 3, j0 = g * 16;
    const int l15 = lane & 15, q = lane >> 4;
    const int bh = blockIdx.x >> 5, c = blockIdx.x & 31;
    const int b = bh >> 4, h = bh & 15;
    const int t0 = c * 64;
    const int bt0 = b * TT + t0;
    const size_t hbb = (size_t)bh * TT * NN;           // head-blocked base
    const size_t cb = (size_t)blockIdx.x * 4096;       // [bh][c] 64x64 tile base

    if (tid < 64) SU[tid] = u[h * NN + tid];

    // ---- phase A0: stage hid_w tile [64t][64k] and w2dec slice [64ch][64k]
#pragma unroll
    for (int rnd = 0; rnd < 2; ++rnd) {
        int ee = rnd * 256 + tid;
        int rw = ee >> 3, c8 = (ee & 7) * 8;
        *(bf16x8*)(HT + rw * PB + c8) =
            *(const bf16x8*)(hidW + (size_t)(bt0 + rw) * 64 + c8);
        *(bf16x8*)(WD + rw * PB + c8) =
            *(const bf16x8*)(w2d + (size_t)(h * 64 + rw) * 64 + c8);
    }
    // r,k,v loads in flight during the lw MFMA (contiguous head-blocked rows)
    const size_t gb = hbb + (size_t)(t0 + row) * 64 + j0;
    bf16x8 r0 = *(const bf16x8*)(r + gb),  r1 = *(const bf16x8*)(r + gb + 8);
    bf16x8 k0 = *(const bf16x8*)(kk + gb), k1 = *(const bf16x8*)(kk + gb + 8);
    bf16x8 v0 = *(const bf16x8*)(vv + gb), v1 = *(const bf16x8*)(vv + gb + 8);
    float tdv[4];
#pragma unroll
    for (int ct = 0; ct < 4; ++ct) tdv[ct] = td[h * 64 + ct * 16 + l15];
    __syncthreads();
    // ---- phase A1: lw tile = hid_w @ w2dec^T ; lw = -exp(td + .)
    {
        bf16x8 aH0 = *(const bf16x8*)(HT + (wq * 16 + l15) * PB + q * 8);
        bf16x8 aH1 = *(const bf16x8*)(HT + (wq * 16 + l15) * PB + q * 8 + 32);
        f32x4 lwa[4] = {};
#pragma unroll
        for (int ct = 0; ct < 4; ++ct) {
            bf16x8 bW0 = *(const bf16x8*)(WD + (ct * 16 + l15) * PB + q * 8);
            bf16x8 bW1 = *(const bf16x8*)(WD + (ct * 16 + l15) * PB + q * 8 + 32);
            lwa[ct] = MFMA(aH0, bW0, lwa[ct]);
            lwa[ct] = MFMA(aH1, bW1, lwa[ct]);
        }
#pragma unroll
        for (int ct = 0; ct < 4; ++ct)
#pragma unroll
            for (int rr = 0; rr < 4; ++rr) {
                int t = wq * 16 + q * 4 + rr, j = ct * 16 + l15;
                LW[t * PW + j] = -expf(tdv[ct] + lwa[ct][rr]);
            }
    }
    __syncthreads();   // LW ready for scan; HT/WD reads done (phase C reuses)
    // ---- phase B: inclusive prefix-sum over t (lane=t), per channel j
    for (int jj = 0; jj < 16; ++jj) {
        int j = wq * 16 + jj;
        float xv = LW[lane * PW + j];
#pragma unroll
        for (int d = 1; d < 64; d <<= 1) {
            float t2 = __shfl_up(xv, d);
            if (lane >= d) xv += t2;
        }
        LW[lane * PW + j] = xv;
    }
    __syncthreads();
    // ---- phase C: build RT, KT, KH, diag, pl
    float rF[16], kF[16];
#pragma unroll
    for (int c2 = 0; c2 < 8; ++c2) {
        rF[c2] = bs2f(r0[c2]); rF[8 + c2] = bs2f(r1[c2]);
        kF[c2] = bs2f(k0[c2]); kF[8 + c2] = bs2f(k1[c2]);
    }
    float cwp[16], cwm[16], cwL[16];
#pragma unroll
    for (int c2 = 0; c2 < 16; ++c2) {
        cwp[c2] = LW[row * PW + j0 + c2];
        cwm[c2] = row ? LW[(row - 1) * PW + j0 + c2] : 0.f;
        cwL[c2] = LW[63 * PW + j0 + c2];
    }
    bf16x8 w0, w1;
#pragma unroll
    for (int c2 = 0; c2 < 8; ++c2) {
        w0[c2] = f2bs(rF[c2] * expf(cwm[c2]));
        w1[c2] = f2bs(rF[8 + c2] * expf(cwm[8 + c2]));
    }
    *(bf16x8*)(RT + row * PB + j0)     = w0;
    *(bf16x8*)(RT + row * PB + j0 + 8) = w1;
    *(bf16x8*)((short*)RTg + cb + row * 64 + j0)     = w0;   // persist for p3
    *(bf16x8*)((short*)RTg + cb + row * 64 + j0 + 8) = w1;
#pragma unroll
    for (int c2 = 0; c2 < 8; ++c2) {
        w0[c2] = f2bs(kF[c2] * expf(-cwp[c2]));
        w1[c2] = f2bs(kF[8 + c2] * expf(-cwp[8 + c2]));
    }
    *(bf16x8*)(KT + row * PB + j0)     = w0;
    *(bf16x8*)(KT + row * PB + j0 + 8) = w1;
#pragma unroll
    for (int c2 = 0; c2 < 16; ++c2)
        KH[(j0 + c2) * PB + row] = f2bs(kF[c2] * expf(cwL[c2] - cwp[c2]));
    if (tid < 64) plg[(size_t)blockIdx.x * 64 + tid] = expf(LW[63 * PW + tid]);
    float dpart = 0.f;
#pragma unroll
    for (int c2 = 0; c2 < 16; ++c2)
        dpart = fmaf(rF[c2] * kF[c2], SU[j0 + c2], dpart);
    dpart += __shfl_xor(dpart, 1);
    dpart += __shfl_xor(dpart, 2);
    if (g == 0) SD[row] = dpart;
    __syncthreads();
    // ---- phase D: VT writes (into dead LW region) + MFMA1 A = RT.KT^T
#pragma unroll
    for (int c2 = 0; c2 < 8; ++c2) {
        VT[(j0 + c2) * PB + row]     = v0[c2];
        VT[(j0 + 8 + c2) * PB + row] = v1[c2];
    }
    bf16x8 aF0 = *(const bf16x8*)(RT + (wq * 16 + l15) * PB + q * 8);
    bf16x8 aF1 = *(const bf16x8*)(RT + (wq * 16 + l15) * PB + q * 8 + 32);
    f32x4 Am[4] = {};
#pragma unroll
    for (int ct = 0; ct < 4; ++ct) {
        bf16x8 bF0 = *(const bf16x8*)(KT + (ct * 16 + l15) * PB + q * 8);
        bf16x8 bF1 = *(const bf16x8*)(KT + (ct * 16 + l15) * PB + q * 8 + 32);
        Am[ct] = MFMA(aF0, bF0, Am[ct]);
        Am[ct] = MFMA(aF1, bF1, Am[ct]);
    }
    __syncthreads();                 // KT reads done -> AT may overlay
#pragma unroll
    for (int ct = 0; ct < 4; ++ct)
#pragma unroll
        for (int rr = 0; rr < 4; ++rr) {
            int s = wq * 16 + q * 4 + rr, p = ct * 16 + l15;
            float vA = Am[ct][rr];
            vA = (p > s) ? 0.f : (p == s ? SD[s] : vA);
            AT[s * PB + p] = f2bs(vA);
        }
    __syncthreads();
    // ---- phase E: Y_local = A.V ; M = VT.KH^T
    f32x4 Y[4] = {}, M[4] = {};
    bf16x8 aA0 = *(const bf16x8*)(AT + (wq * 16 + l15) * PB + q * 8);
    bf16x8 aA1 = *(const bf16x8*)(AT + (wq * 16 + l15) * PB + q * 8 + 32);
    bf16x8 aV0 = *(const bf16x8*)(VT + (wq * 16 + l15) * PB + q * 8);
    bf16x8 aV1 = *(const bf16x8*)(VT + (wq * 16 + l15) * PB + q * 8 + 32);
#pragma unroll
    for (int ct = 0; ct < 4; ++ct) {
        bf16x8 bV0 = *(const bf16x8*)(VT + (ct * 16 + l15) * PB + q * 8);
        bf16x8 bV1 = *(const bf16x8*)(VT + (ct * 16 + l15) * PB + q * 8 + 32);
        Y[ct] = MFMA(aA0, bV0, Y[ct]);
        Y[ct] = MFMA(aA1, bV1, Y[ct]);
        bf16x8 bK0 = *(const bf16x8*)(KH + (ct * 16 + l15) * PB + q * 8);
        bf16x8 bK1 = *(const bf16x8*)(KH + (ct * 16 + l15) * PB + q * 8 + 32);
        M[ct] = MFMA(aV0, bK0, M[ct]);
        M[ct] = MFMA(aV1, bK1, M[ct]);
    }
    __syncthreads();                 // all VT reads done -> Y may overlay VT
#pragma unroll
    for (int ct = 0; ct < 4; ++ct)
#pragma unroll
        for (int rr = 0; rr < 4; ++rr) {
            int s = wq * 16 + q * 4 + rr;
            VT[s * PB + ct * 16 + l15] = f2bs(Y[ct][rr]);   // stage Y
            Mg[cb + (size_t)s * 64 + ct * 16 + l15] = f2bs(M[ct][rr]);
        }
    __syncthreads();
    // coalesced y write: 2 iters x 256 thr x 16 B contiguous hb stores
#pragma unroll
    for (int it = 0; it < 2; ++it) {
        int gidx = it * 256 + tid;           // 512 units of 16 B
        int rY = gidx >> 3, cB = (gidx & 7) * 8;
        *(bf16x8*)((short*)y + hbb + (size_t)(t0 + rY) * 64 + cB) =
            *(const bf16x8*)(VT + rY * PB + cB);
    }
}

// ---------------------------------------------------------------------------
// Pass 2: sequential scan over 32 chunks, elementwise on S[i][j] per (b,h).
// ---------------------------------------------------------------------------
__global__ __launch_bounds__(256) void k_wkv_p2(const short* __restrict__ Mg,
                                                const float* __restrict__ plg,
                                                bf16* __restrict__ Sg)
{
    int bh = blockIdx.x >> 4, part = blockIdx.x & 15;
    int i = part * 4 + (threadIdx.x >> 6), j = threadIdx.x & 63;
    float S = 0.f;
    size_t eb = (size_t)bh * 32 * 4096 + (size_t)i * 64 + j;
    size_t pb = (size_t)bh * 32 * 64 + j;
    for (int c = 0; c < 32; ++c) {
        Sg[eb + (size_t)c * 4096] = __float2bfloat16(S);
        S = plg[pb + (size_t)c * 64] * S + bs2f(Mg[eb + (size_t)c * 4096]);
    }
}

// ---------------------------------------------------------------------------
// Pass 3: gate tile G = hid_g @ gate_w2^T (MFMA, frag-aligned with Y);
// Y = Y_local + RT.S_in (MFMA); fused groupnorm-over-head * G -> A2.
// y read head-blocked; A2 written blk128 via LDS-staged coalesced epilogue.
// ---------------------------------------------------------------------------
__global__ __launch_bounds__(256) void k_wkv_p3(const bf16* __restrict__ RTg,
                                                const bf16* __restrict__ Sg,
                                                const bf16* __restrict__ y,
                                                const bf16* __restrict__ hidG,
                                                const bf16* __restrict__ w2g,
                                                const float* __restrict__ ln_g,
                                                const float* __restrict__ ln_b,
                                                bf16* __restrict__ A2)
{
    constexpr int PB = 72;
    __shared__ __align__(16) short BufA[64 * PB], BufB[64 * PB];
    const int tid = threadIdx.x;
    const int lane = tid & 63, wq = tid >> 6;
    const int l15 = lane & 15, q = lane >> 4;
    const int bh = blockIdx.x >> 5, c = blockIdx.x & 31;
    const int b = bh >> 4, h = bh & 15;
    const int t0 = c * 64;
    const int bt0 = b * TT + t0;
    const size_t hbb = (size_t)bh * TT * NN;
    const size_t cb = (size_t)blockIdx.x * 4096;

    // ---- stage hid_g tile + gate_w2 slice; compute G frags
#pragma unroll
    for (int rnd = 0; rnd < 2; ++rnd) {
        int ee = rnd * 256 + tid;
        int rw = ee >> 3, c8 = (ee & 7) * 8;
        *(bf16x8*)(BufA + rw * PB + c8) =
            *(const bf16x8*)(hidG + (size_t)(bt0 + rw) * 64 + c8);
        *(bf16x8*)(BufB + rw * PB + c8) =
            *(const bf16x8*)(w2g + (size_t)(h * 64 + rw) * 64 + c8);
    }
    __syncthreads();
    f32x4 G[4] = {};
    {
        bf16x8 aH0 = *(const bf16x8*)(BufA + (wq * 16 + l15) * PB + q * 8);
        bf16x8 aH1 = *(const bf16x8*)(BufA + (wq * 16 + l15) * PB + q * 8 + 32);
#pragma unroll
        for (int ct = 0; ct < 4; ++ct) {
            bf16x8 bW0 = *(const bf16x8*)(BufB + (ct * 16 + l15) * PB + q * 8);
            bf16x8 bW1 = *(const bf16x8*)(BufB + (ct * 16 + l15) * PB + q * 8 + 32);
            G[ct] = MFMA(aH0, bW0, G[ct]);
            G[ct] = MFMA(aH1, bW1, G[ct]);
        }
    }
    __syncthreads();
    // ---- stage RT + S_in
#pragma unroll
    for (int rnd = 0; rnd < 2; ++rnd) {
        int ee = rnd * 256 + tid;
        int rw = ee >> 3, c8 = (ee & 7) * 8;
        *(bf16x8*)(BufA + rw * PB + c8) =
            *(const bf16x8*)((const short*)RTg + cb + rw * 64 + c8);
        *(bf16x8*)(BufB + rw * PB + c8) =
            *(const bf16x8*)((const short*)Sg + cb + rw * 64 + c8);
    }
    __syncthreads();

    // preload Y_local into C frags, accumulate cross term on top
    f32x4 Yc[4];
#pragma unroll
    for (int ct = 0; ct < 4; ++ct)
#pragma unroll
        for (int rr = 0; rr < 4; ++rr) {
            int s = wq * 16 + q * 4 + rr;
            Yc[ct][rr] = __bfloat162float(
                y[hbb + (size_t)(t0 + s) * 64 + ct * 16 + l15]);
        }
    bf16x8 aF0 = *(const bf16x8*)(BufA + (wq * 16 + l15) * PB + q * 8);
    bf16x8 aF1 = *(const bf16x8*)(BufA + (wq * 16 + l15) * PB + q * 8 + 32);
#pragma unroll
    for (int ct = 0; ct < 4; ++ct) {
        bf16x8 bS0 = *(const bf16x8*)(BufB + (ct * 16 + l15) * PB + q * 8);
        bf16x8 bS1 = *(const bf16x8*)(BufB + (ct * 16 + l15) * PB + q * 8 + 32);
        Yc[ct] = MFMA(aF0, bS0, Yc[ct]);
        Yc[ct] = MFMA(aF1, bS1, Yc[ct]);
    }
    __syncthreads();                 // BufA/BufB reads done -> stage A2 in BufA
    // groupnorm over the 64 head channels (cols = ct*16+l15) per row s, * G
#pragma unroll
    for (int rr = 0; rr < 4; ++rr) {
        float s1 = 0.f, s2 = 0.f;
#pragma unroll
        for (int ct = 0; ct < 4; ++ct) {
            float vA = Yc[ct][rr];
            s1 += vA; s2 += vA * vA;
        }
#pragma unroll
        for (int o = 1; o < 16; o <<= 1) {
            s1 += __shfl_xor(s1, o);
            s2 += __shfl_xor(s2, o);
        }
        float mu  = s1 * (1.f / 64.f);
        float var = s2 * (1.f / 64.f) - mu * mu;
        float rstd = rsqrtf(var + 6.4e-4f);
        int s = wq * 16 + q * 4 + rr;
#pragma unroll
        for (int ct = 0; ct < 4; ++ct) {
            int ch = h * NN + ct * 16 + l15;
            float yn = (Yc[ct][rr] - mu) * rstd;
            float outv = (yn * ln_g[ch] + ln_b[ch]) * G[ct][rr];
            BufA[s * PB + ct * 16 + l15] = f2bs(outv);       // stage A2 tile
        }
    }
    __syncthreads();
    // coalesced A2 write into blk128 image: rows bt0..+63, ktile h.
    // Per kg, 64 rows x 8 shorts contiguous; lanes sweep rows -> 1 KB runs.
    {
        const size_t tb = ((size_t)((bt0) >> 7) * 16 + h) * 8192;
        const int rowbase = bt0 & 127;               // 0 or 64
#pragma unroll
        for (int it = 0; it < 2; ++it) {
            int gidx = it * 256 + tid;               // 512 units of 16 B
            int kg = gidx >> 6, rA = gidx & 63;
            *(bf16x8*)((short*)A2 + tb + kg * 1024 + (size_t)(rowbase + rA) * 8) =
                *(const bf16x8*)(BufA + rA * PB + kg * 8);
        }
    }
}

// g_out: 512 blocks, XCD swizzle with n FASTEST within m-groups: each group
// of 8 consecutive blocks shares the 256 KB A2 m-panel (L2 hit), and the
// whole 2 MB WoT stays L2-resident per XCD. 512 % 8 == 0: bijective.
__global__ __launch_bounds__(256) void g_out(const bf16* __restrict__ A2,
                                             const bf16* __restrict__ WoT,
                                             float* __restrict__ out)
{
    __shared__ __align__(16) short lds[32768];
    int bid = blockIdx.x;
    int swz = (bid & 7) * 64 + (bid >> 3);
    int m0 = (swz >> 3) * 128, n0 = (swz & 7) * 128;
    gemm128b(lds, lds + 16384, A2, WoT, CC / 64, m0, n0,
             [&](int m, int n, float v) { out[(size_t)m * CC + n] = v; });
}

// ---------------------------------------------------------------------------
extern "C" void kernel_launch(void* const* d_in, const int* in_sizes, int n_in,
                              void* d_out, int out_size, void* d_ws, size_t ws_size,
                              hipStream_t stream)
{
    const float* x        = (const float*)d_in[0];
    const float* maa_x    = (const float*)d_in[1];
    const float* maa_w    = (const float*)d_in[2];
    const float* maa_k    = (const float*)d_in[3];
    const float* maa_v    = (const float*)d_in[4];
    const float* maa_r    = (const float*)d_in[5];
    const float* maa_g    = (const float*)d_in[6];
    const float* maa_w1   = (const float*)d_in[7];
    const float* maa_w2   = (const float*)d_in[8];
    const float* Wr       = (const float*)d_in[9];
    const float* Wk       = (const float*)d_in[10];
    const float* Wv       = (const float*)d_in[11];
    const float* Wo       = (const float*)d_in[12];
    const float* gate_w1  = (const float*)d_in[13];
    const float* gate_w2  = (const float*)d_in[14];
    const float* time_dec = (const float*)d_in[15];
    const float* decay_w1 = (const float*)d_in[16];
    const float* decay_w2 = (const float*)d_in[17];
    const float* u        = (const float*)d_in[18];
    const float* ln_g     = (const float*)d_in[19];
    const float* ln_b     = (const float*)d_in[20];

    // --- workspace layout with lifetime reuse ---
    size_t off = 0;
    auto alloc = [&](size_t bytes) {
        off = (off + 255) & ~(size_t)255;
        void* p = (char*)d_ws + off;
        off += bytes;
        return p;
    };
    bf16*  WT3   = (bf16*) alloc(3ull * CC * CC * 2);       // WrT,WkT,WvT (blk256)
    bf16*  WoT   = (bf16*) alloc((size_t)CC * CC * 2);      // blk128
    bf16*  w1T   = (bf16*) alloc(256ull * CC * 2);          // maa_w1^T padded
    bf16*  w1T2  = (bf16*) alloc(2ull * 128 * CC * 2);      // gate_w1^T, decay_w1^T
    bf16*  w2T2  = (bf16*) alloc(2ull * CC * 64 * 2);       // gate_w2^T, decay_w2^T
    bf16*  w2T5  = (bf16*) alloc(5ull * CC * 32 * 2);       // maa_w2[f]^T
    float* maas  = (float*)alloc(5ull * CC * 4);
    // bufA 16 MB: xxx (dead after g_lora) -> A2 blk128 (written by p3)
    char* bufA = (char*)alloc((size_t)BT * CC * 2);
    bf16* xxxbf = (bf16*)bufA;
    bf16* A2    = (bf16*)bufA;
    // bufB 2.56 MB: lora (dead after g_xvar) -> hid (2 MB, lives through p3)
    char* bufB = (char*)alloc((size_t)BT * 160 * 2);
    bf16* Lbf  = (bf16*)bufB;
    bf16* hid  = (bf16*)bufB;
    // bufC 80 MB: xvars blocked (dead after g_rkv5) -> ybuf bf16(16M) | RTg(16.8M)
    char* bufC = (char*)alloc(5ull * BT * CC * 2);
    bf16*  xvars = (bf16*)bufC;
    bf16*  ybuf  = (bf16*)bufC;
    bf16*  RTg   = (bf16*)(bufC + (size_t)BT * CC * 2);
    // bufD 48 MB: r,k,v bf16 (dead after p1) -> S_in bf16 (16.8M, by p2)
    bf16*  rkv  = (bf16*)alloc(3ull * BT * CC * 2);
    bf16*  Sg   = rkv;
    // xb/xxb bf16 packs (16 MB each), Mg bf16 (16.8 MB), pl fp32 (0.5 MB)
    bf16*  xb   = (bf16*) alloc((size_t)BT * CC * 2);
    bf16*  xxb  = (bf16*) alloc((size_t)BT * CC * 2);
    short* Mg   = (short*)alloc(64ull * 32 * 4096 * 2);
    float* plg  = (float*)alloc(64ull * 32 * 64 * 4);

    // --- single fused prep launch (weights + xxx/xb/xxb) ---
    k_prep_all<<<dim3(13092), 256, 0, stream>>>(
        Wr, Wk, Wv, Wo, maa_w1, gate_w1, decay_w1, gate_w2, decay_w2, maa_w2,
        maa_w, maa_k, maa_v, maa_r, maa_g, x, maa_x,
        WT3, WoT, w1T, w1T2, w2T2, w2T5, maas, xxxbf, xb, xxb);

    // --- forward pipeline ---
    g_lora<<<dim3(64, 2), 256, 0, stream>>>(xxxbf, w1T, Lbf);
    g_xvar<<<dim3(64, 8), 256, 0, stream>>>(Lbf, w2T5, maas, xb, xxb, xvars);
    g_rkv5<<<dim3(448), 512, 0, stream>>>(xvars, WT3, w1T2, rkv, hid);
    k_wkv_p1<<<dim3(2048), 256, 0, stream>>>(rkv, rkv + (size_t)BT * CC,
                                             rkv + 2ull * BT * CC,
                                             hid + (size_t)BT * 64,   // hid_w
                                             w2T2 + CC * 64,          // decay_w2^T
                                             time_dec, u, ybuf, RTg, Mg, plg);
    k_wkv_p2<<<dim3(1024), 256, 0, stream>>>(Mg, plg, Sg);
    k_wkv_p3<<<dim3(2048), 256, 0, stream>>>(RTg, Sg, ybuf,
                                             hid,                     // hid_g
                                             w2T2,                    // gate_w2^T
                                             ln_g, ln_b, A2);
    g_out<<<dim3(512), 256, 0, stream>>>(A2, WoT, (float*)d_out);
}

// Round 11
// 356.582 us; speedup vs baseline: 1.0194x; 1.0194x over previous
//
#include <hip/hip_runtime.h>
#include <hip/hip_bf16.h>
#include <stdint.h>

typedef __hip_bfloat16 bf16;
typedef __attribute__((ext_vector_type(8))) short bf16x8;   // 8 bf16 = 4 VGPRs (MFMA A/B frag)
typedef __attribute__((ext_vector_type(4))) float f32x4;    // MFMA C/D frag

#define CC 1024
#define TT 2048
#define BB 4
#define BT 8192     // BB*TT
#define HH 16
#define NN 64       // head size

#define MFMA(a, b, c) __builtin_amdgcn_mfma_f32_16x16x32_bf16(a, b, c, 0, 0, 0)

// async global->LDS, 16B per lane. Direct addrspace casts (addrspacecast),
// NOT via uintptr_t (inttoptr of flat addr -> garbage LDS offset -> fault).
#define GLD(g, l) __builtin_amdgcn_global_load_lds( \
    (const __attribute__((address_space(1))) void*)(g), \
    (__attribute__((address_space(3))) void*)(l), 16, 0, 0)

__device__ __forceinline__ short f2bs(float f) {
    bf16 h = __float2bfloat16(f);
    return *reinterpret_cast<short*>(&h);
}
__device__ __forceinline__ float bs2f(short s) {
    bf16 h = *reinterpret_cast<bf16*>(&s);
    return __bfloat162float(h);
}

// Blocked-tile index, 256-row tiles (xvars, WrT/WkT/WvT): tile (m>>8,k>>6) is
// 16384 contiguous elems, internal [kg8][row256][col8] == the LDS image of
// gemm256 staging, so GLD sweeps are fully contiguous.
__device__ __forceinline__ size_t blk_idx(int m, int k, int ktiles) {
    return ((size_t)(m >> 8) * ktiles + (k >> 6)) * 16384
         + ((k >> 3) & 7) * 2048 + (m & 255) * 8 + (k & 7);
}

// Blocked-tile index, 128-row tiles (A2, WoT): tile (m>>7,k>>6) is 8192
// contiguous elems, internal [kg8][row128][col8] == gemm128b LDS image.
__device__ __forceinline__ size_t blk128_idx(int m, int k, int ktiles) {
    return ((size_t)(m >> 7) * ktiles + (k >> 6)) * 8192
         + ((k >> 3) & 7) * 1024 + (m & 127) * 8 + (k & 7);
}

// ---------------------------------------------------------------------------
// 128x128 MFMA GEMM core, BK=64, 2-phase dbuf, LINEAR row-major inputs.
// R3 schedule (stage-early, one barrier/K-step). Used by g_lora.
// ---------------------------------------------------------------------------
template <typename EPI>
__device__ __forceinline__ void gemm128L(short* As, short* Bs,
                                         const bf16* __restrict__ A, int lda,
                                         const bf16* __restrict__ Bt, int ldb,
                                         int kiters, int m0, int n0, EPI epi)
{
    const int tid = threadIdx.x;
    const int l   = tid & 63, wv = tid >> 6;
    const int wm  = wv >> 1, wn = wv & 1;
    const int q   = l >> 4, lr = l & 15;
    const int row = tid & 127, kg1 = tid >> 7;

    f32x4 acc[4][4] = {};

    const bf16* ga = A  + (size_t)(m0 + row) * lda + kg1 * 8;
    const bf16* gb = Bt + (size_t)(n0 + row) * ldb + kg1 * 8;

    auto stage = [&](int kb, int u) {
        const bf16* gak = ga + kb * 64;
        const bf16* gbk = gb + kb * 64;
        short* la = As + u * 8192 + tid * 8;
        short* lb = Bs + u * 8192 + tid * 8;
        GLD(gak,      la);
        GLD(gak + 16, la + 2048);
        GLD(gak + 32, la + 4096);
        GLD(gak + 48, la + 6144);
        GLD(gbk,      lb);
        GLD(gbk + 16, lb + 2048);
        GLD(gbk + 32, lb + 4096);
        GLD(gbk + 48, lb + 6144);
    };

    __syncthreads();
    stage(0, 0);
    __syncthreads();
    for (int kb = 0; kb < kiters; ++kb) {
        const int cur = kb & 1;
        if (kb + 1 < kiters) stage(kb + 1, cur ^ 1);   // prefetch next K-tile
        const short* Ac = As + cur * 8192;
        const short* Bc = Bs + cur * 8192;
        bf16x8 af[2][4], bfb[2][4];
#pragma unroll
        for (int hh = 0; hh < 2; ++hh) {
#pragma unroll
            for (int mt = 0; mt < 4; ++mt)
                af[hh][mt] = *(const bf16x8*)(Ac +
                    ((q + hh * 4) * 128 + wm * 64 + mt * 16 + lr) * 8);
#pragma unroll
            for (int nt = 0; nt < 4; ++nt)
                bfb[hh][nt] = *(const bf16x8*)(Bc +
                    ((q + hh * 4) * 128 + wn * 64 + nt * 16 + lr) * 8);
        }
        __builtin_amdgcn_s_setprio(1);
#pragma unroll
        for (int mt = 0; mt < 4; ++mt)
#pragma unroll
            for (int nt = 0; nt < 4; ++nt) {
                acc[mt][nt] = MFMA(af[0][mt], bfb[0][nt], acc[mt][nt]);
                acc[mt][nt] = MFMA(af[1][mt], bfb[1][nt], acc[mt][nt]);
            }
        __builtin_amdgcn_s_setprio(0);
        __syncthreads();
    }
#pragma unroll
    for (int mt = 0; mt < 4; ++mt)
#pragma unroll
        for (int nt = 0; nt < 4; ++nt)
#pragma unroll
            for (int rr = 0; rr < 4; ++rr)
                epi(m0 + wm * 64 + mt * 16 + q * 4 + rr,
                    n0 + wn * 64 + nt * 16 + lr, acc[mt][nt][rr]);
}

// ---------------------------------------------------------------------------
// 128x128 MFMA GEMM core, BK=64, 2-phase dbuf, BLOCKED inputs (blk128_idx).
// R3 schedule. Used by g_out.
// ---------------------------------------------------------------------------
template <typename EPI>
__device__ __forceinline__ void gemm128b(short* As, short* Bs,
                                         const bf16* __restrict__ A,
                                         const bf16* __restrict__ Bt,
                                         int kiters, int m0, int n0, EPI epi)
{
    const int tid = threadIdx.x;
    const int l   = tid & 63, wv = tid >> 6;
    const int wm  = wv >> 1, wn = wv & 1;
    const int q   = l >> 4, lr = l & 15;

    f32x4 acc[4][4] = {};

    const bf16* ga = A  + (size_t)(m0 >> 7) * 16 * 8192 + tid * 8;
    const bf16* gb = Bt + (size_t)(n0 >> 7) * 16 * 8192 + tid * 8;

    auto stage = [&](int kb, int u) {
        const bf16* gak = ga + (size_t)kb * 8192;
        const bf16* gbk = gb + (size_t)kb * 8192;
        short* la = As + u * 8192 + tid * 8;
        short* lb = Bs + u * 8192 + tid * 8;
        GLD(gak,        la);
        GLD(gak + 2048, la + 2048);
        GLD(gak + 4096, la + 4096);
        GLD(gak + 6144, la + 6144);
        GLD(gbk,        lb);
        GLD(gbk + 2048, lb + 2048);
        GLD(gbk + 4096, lb + 4096);
        GLD(gbk + 6144, lb + 6144);
    };

    __syncthreads();
    stage(0, 0);
    __syncthreads();
    for (int kb = 0; kb < kiters; ++kb) {
        const int cur = kb & 1;
        if (kb + 1 < kiters) stage(kb + 1, cur ^ 1);   // prefetch next K-tile
        const short* Ac = As + cur * 8192;
        const short* Bc = Bs + cur * 8192;
        bf16x8 af[2][4], bfb[2][4];
#pragma unroll
        for (int hh = 0; hh < 2; ++hh) {
#pragma unroll
            for (int mt = 0; mt < 4; ++mt)
                af[hh][mt] = *(const bf16x8*)(Ac +
                    ((q + hh * 4) * 128 + wm * 64 + mt * 16 + lr) * 8);
#pragma unroll
            for (int nt = 0; nt < 4; ++nt)
                bfb[hh][nt] = *(const bf16x8*)(Bc +
                    ((q + hh * 4) * 128 + wn * 64 + nt * 16 + lr) * 8);
        }
        __builtin_amdgcn_s_setprio(1);
#pragma unroll
        for (int mt = 0; mt < 4; ++mt)
#pragma unroll
            for (int nt = 0; nt < 4; ++nt) {
                acc[mt][nt] = MFMA(af[0][mt], bfb[0][nt], acc[mt][nt]);
                acc[mt][nt] = MFMA(af[1][mt], bfb[1][nt], acc[mt][nt]);
            }
        __builtin_amdgcn_s_setprio(0);
        __syncthreads();
    }
#pragma unroll
    for (int mt = 0; mt < 4; ++mt)
#pragma unroll
        for (int nt = 0; nt < 4; ++nt)
#pragma unroll
            for (int rr = 0; rr < 4; ++rr)
                epi(m0 + wm * 64 + mt * 16 + q * 4 + rr,
                    n0 + wn * 64 + nt * 16 + lr, acc[mt][nt][rr]);
}

// ---------------------------------------------------------------------------
// 256x256 MFMA GEMM core, BK=64, 512 threads (8 waves, 2x4), 2-phase dbuf,
// R3 schedule — proven optimum for this kernel (R4/R8 schedule variants both
// regressed; occupancy >1 block/CU impossible: acc=128 AGPR/wave). A and Bt
// BLOCKED (blk_idx). Output head-blocked via LDS-staged coalesced epilogue.
// ---------------------------------------------------------------------------
__device__ __forceinline__ void gemm256(short* lds,
                                        const bf16* __restrict__ A,
                                        const bf16* __restrict__ Bt,
                                        int kiters, int m0, int n0,
                                        bf16* __restrict__ out)
{
    short* As = lds;
    short* Bs = lds + 32768;
    const int tid = threadIdx.x;            // 0..511
    const int l   = tid & 63, wv = tid >> 6;
    const int wm  = wv >> 2, wn = wv & 3;   // 2 x 4 wave grid
    const int q   = l >> 4, lr = l & 15;

    f32x4 acc[8][4] = {};

    const bf16* ga = A  + (size_t)(m0 >> 8) * 16 * 16384 + tid * 8;
    const bf16* gb = Bt + (size_t)(n0 >> 8) * 16 * 16384 + tid * 8;

    auto stage = [&](int kb, int u) {
        const bf16* gak = ga + (size_t)kb * 16384;
        const bf16* gbk = gb + (size_t)kb * 16384;
        short* la = As + u * 16384 + tid * 8;
        short* lb = Bs + u * 16384 + tid * 8;
        GLD(gak,         la);
        GLD(gak + 4096,  la + 4096);
        GLD(gak + 8192,  la + 8192);
        GLD(gak + 12288, la + 12288);
        GLD(gbk,         lb);
        GLD(gbk + 4096,  lb + 4096);
        GLD(gbk + 8192,  lb + 8192);
        GLD(gbk + 12288, lb + 12288);
    };

    __syncthreads();
    stage(0, 0);
    __syncthreads();
    for (int kb = 0; kb < kiters; ++kb) {
        const int cur = kb & 1;
        if (kb + 1 < kiters) stage(kb + 1, cur ^ 1);
        const short* Ac = As + cur * 16384;
        const short* Bc = Bs + cur * 16384;
#pragma unroll
        for (int hh = 0; hh < 2; ++hh) {    // per-k-half to bound VGPR
            bf16x8 af[8], bfb[4];
#pragma unroll
            for (int mt = 0; mt < 8; ++mt)
                af[mt] = *(const bf16x8*)(Ac +
                    ((q + hh * 4) * 256 + wm * 128 + mt * 16 + lr) * 8);
#pragma unroll
            for (int nt = 0; nt < 4; ++nt)
                bfb[nt] = *(const bf16x8*)(Bc +
                    ((q + hh * 4) * 256 + wn * 64 + nt * 16 + lr) * 8);
            __builtin_amdgcn_s_setprio(1);
#pragma unroll
            for (int mt = 0; mt < 8; ++mt)
#pragma unroll
                for (int nt = 0; nt < 4; ++nt)
                    acc[mt][nt] = MFMA(af[mt], bfb[nt], acc[mt][nt]);
            __builtin_amdgcn_s_setprio(0);
        }
        __syncthreads();
    }
    // ---- LDS-staged epilogue (dbuf LDS is dead; overlay [256][268] bf16) ----
    constexpr int EP = 268;                 // pad: q-groups hit disjoint banks
    short* E = lds;
#pragma unroll
    for (int mt = 0; mt < 8; ++mt)
#pragma unroll
        for (int nt = 0; nt < 4; ++nt)
#pragma unroll
            for (int rr = 0; rr < 4; ++rr) {
                int r    = wm * 128 + mt * 16 + q * 4 + rr;
                int ccol = wn * 64 + nt * 16 + lr;
                E[r * EP + ccol] = f2bs(acc[mt][nt][rr]);
            }
    __syncthreads();
    const int b     = m0 >> 11;             // batch
    const int hbase = n0 >> 6;              // first head of this n-tile
#pragma unroll
    for (int it = 0; it < 16; ++it) {
        int gidx = it * 512 + tid;          // 16-B units, 8192 total
        int hh   = gidx >> 11;              // head 0..3 (constant per wave)
        int u    = gidx & 2047;
        int r    = u >> 3;                  // row 0..255
        int cB   = (u & 7) * 8;             // col base (shorts)
        bf16x8 vdat = *(const bf16x8*)(E + r * EP + hh * 64 + cB);
        size_t o = (((size_t)(b * 16 + hbase + hh)) * 2048
                    + (size_t)((m0 & 2047) + r)) * 64 + cB;
        *(bf16x8*)((short*)out + o) = vdat;
    }
}

// ---------------------------------------------------------------------------
// 256x64 hidden-GEMM core (gate/decay), 512 threads, R3 schedule.
// A is BLOCKED (xvars layout); B = w1T2 slice stays linear (tiny traffic).
// ---------------------------------------------------------------------------
template <typename EPI>
__device__ __forceinline__ void gemmHid(short* As, short* Bs,
                                        const bf16* __restrict__ A,
                                        const bf16* __restrict__ Bt, int ldb,
                                        int kiters, int m0, EPI epi)
{
    const int tid = threadIdx.x;
    const int l   = tid & 63, wv = tid >> 6;    // wave -> 32-row slab
    const int q   = l >> 4, lr = l & 15;
    const int row64 = tid & 63, kg8 = tid >> 6; // B staging: 64 rows x 8 kgroups

    f32x4 acc[2][4] = {};

    const bf16* ga = A + (size_t)(m0 >> 8) * 16 * 16384 + tid * 8;
    const bf16* gb = Bt + (size_t)row64 * ldb + kg8 * 8;

    auto stage = [&](int kb, int u) {
        const bf16* gak = ga + (size_t)kb * 16384;
        short* la = As + u * 16384 + tid * 8;
        GLD(gak,         la);
        GLD(gak + 4096,  la + 4096);
        GLD(gak + 8192,  la + 8192);
        GLD(gak + 12288, la + 12288);
        GLD(gb + kb * 64, Bs + u * 4096 + tid * 8);
    };

    __syncthreads();
    stage(0, 0);
    __syncthreads();
    for (int kb = 0; kb < kiters; ++kb) {
        const int cur = kb & 1;
        if (kb + 1 < kiters) stage(kb + 1, cur ^ 1);
        const short* Ac = As + cur * 16384;
        const short* Bc = Bs + cur * 4096;
        bf16x8 af[2][2], bfb[2][4];
#pragma unroll
        for (int hh = 0; hh < 2; ++hh) {
#pragma unroll
            for (int mt = 0; mt < 2; ++mt)
                af[hh][mt] = *(const bf16x8*)(Ac +
                    ((q + hh * 4) * 256 + wv * 32 + mt * 16 + lr) * 8);
#pragma unroll
            for (int nt = 0; nt < 4; ++nt)
                bfb[hh][nt] = *(const bf16x8*)(Bc +
                    ((q + hh * 4) * 64 + nt * 16 + lr) * 8);
        }
#pragma unroll
        for (int mt = 0; mt < 2; ++mt)
#pragma unroll
            for (int nt = 0; nt < 4; ++nt) {
                acc[mt][nt] = MFMA(af[0][mt], bfb[0][nt], acc[mt][nt]);
                acc[mt][nt] = MFMA(af[1][mt], bfb[1][nt], acc[mt][nt]);
            }
        __syncthreads();
    }
#pragma unroll
    for (int mt = 0; mt < 2; ++mt)
#pragma unroll
        for (int nt = 0; nt < 4; ++nt)
#pragma unroll
            for (int rr = 0; rr < 4; ++rr)
                epi(m0 + wv * 32 + mt * 16 + q * 4 + rr,
                    nt * 16 + lr, acc[mt][nt][rr]);
}

// ---------------------------------------------------------------------------
// ALL prep in one launch: 13092 blocks (weights transpose + xxx/xb/xxb).
// WrT/WkT/WvT -> blk_idx layout; WoT -> blk128_idx layout; rest linear.
// ---------------------------------------------------------------------------
__global__ __launch_bounds__(256) void k_prep_all(
    const float* __restrict__ Wr, const float* __restrict__ Wk,
    const float* __restrict__ Wv, const float* __restrict__ Wo,
    const float* __restrict__ maa_w1, const float* __restrict__ gate_w1,
    const float* __restrict__ decay_w1, const float* __restrict__ gate_w2,
    const float* __restrict__ decay_w2, const float* __restrict__ maa_w2,
    const float* __restrict__ mw, const float* __restrict__ mk,
    const float* __restrict__ mv, const float* __restrict__ mr,
    const float* __restrict__ mg, const float* __restrict__ x,
    const float* __restrict__ maa_x,
    bf16* __restrict__ WT3, bf16* __restrict__ WoT, bf16* __restrict__ w1T,
    bf16* __restrict__ w1T2, bf16* __restrict__ w2T2, bf16* __restrict__ w2T5,
    float* __restrict__ maas, bf16* __restrict__ xxx,
    bf16* __restrict__ xb, bf16* __restrict__ xxb)
{
    __shared__ float tile[32][33];
    int idx = blockIdx.x;
    if (idx >= 4900) {                       // xb=x, xxb=shift(x)-x, xxx=x+xx*maa_x
        size_t i = ((size_t)(idx - 4900) * 256 + threadIdx.x) * 4;
        int cc = i & (CC - 1);
        int t  = (i >> 10) & (TT - 1);
        float4 xm = *(const float4*)(x + i);
        float4 xp = t ? *(const float4*)(x + i - CC)
                      : make_float4(0.f, 0.f, 0.f, 0.f);
        float4 ax = *(const float4*)(maa_x + cc);
        float xxv[4] = {xp.x - xm.x, xp.y - xm.y, xp.z - xm.z, xp.w - xm.w};
        float xmv[4] = {xm.x, xm.y, xm.z, xm.w};
        float axv[4] = {ax.x, ax.y, ax.z, ax.w};
#pragma unroll
        for (int e = 0; e < 4; ++e) {
            xb[i + e]  = __float2bfloat16(xmv[e]);
            xxb[i + e] = __float2bfloat16(xxv[e]);
            xxx[i + e] = __float2bfloat16(xmv[e] + xxv[e] * axv[e]);
        }
        return;
    }
    const float* src; bf16* dst; int rows, cols_in, tx_;
    int blkmode = 0;                         // 0=linear, 1=blk256, 2=blk128
    if (idx < 4096) {
        int s = idx >> 10; idx &= 1023;
        src = (s == 0) ? Wr : (s == 1) ? Wk : (s == 2) ? Wv : Wo;
        dst = (s == 3) ? WoT : WT3 + (size_t)s * CC * CC;
        blkmode = (s == 3) ? 2 : 1;
        rows = CC; cols_in = CC; tx_ = 32;
    } else if (idx < 4352) { idx -= 4096; src = maa_w1;  dst = w1T;  rows = CC; cols_in = 160; tx_ = 8; }
    else if (idx < 4480)   { idx -= 4352; src = gate_w1; dst = w1T2; rows = CC; cols_in = 64;  tx_ = 4; }
    else if (idx < 4608)   { idx -= 4480; src = decay_w1; dst = w1T2 + 128 * CC; rows = CC; cols_in = 64; tx_ = 4; }
    else if (idx < 4672)   { idx -= 4608; src = gate_w2;  dst = w2T2;           rows = 64; cols_in = CC; tx_ = 32; }
    else if (idx < 4736)   { idx -= 4672; src = decay_w2; dst = w2T2 + CC * 64; rows = 64; cols_in = CC; tx_ = 32; }
    else if (idx < 4896)   { idx -= 4736; int f = idx >> 5; idx &= 31;
                             src = maa_w2 + (size_t)f * 32 * CC;
                             dst = w2T5 + (size_t)f * CC * 32; rows = 32; cols_in = CC; tx_ = 32; }
    else {
        int i = (idx - 4896) * 256 + threadIdx.x;
        if (i < CC) {
            maas[i]          = mw[i];
            maas[CC + i]     = mk[i];
            maas[2 * CC + i] = mv[i];
            maas[3 * CC + i] = mr[i];
            maas[4 * CC + i] = mg[i];
        }
        return;
    }
    int bx = idx % tx_, by = idx / tx_;
    int c0 = bx * 32, r0 = by * 32;
    int tx = threadIdx.x & 31, ty = threadIdx.x >> 5;
    for (int i = ty; i < 32; i += 8) {
        int cc2 = c0 + tx;
        tile[i][tx] = (cc2 < cols_in) ? src[(size_t)(r0 + i) * cols_in + cc2] : 0.f;
    }
    __syncthreads();
    if (blkmode == 1) {
        for (int i = ty; i < 32; i += 8) {
            int R = c0 + i, C = r0 + tx;             // out row (n), k col
            dst[blk_idx(R, C, 16)] = __float2bfloat16(tile[tx][i]);
        }
    } else if (blkmode == 2) {
        for (int i = ty; i < 32; i += 8) {
            int R = c0 + i, C = r0 + tx;
            dst[blk128_idx(R, C, 16)] = __float2bfloat16(tile[tx][i]);
        }
    } else {
        for (int i = ty; i < 32; i += 8)
            dst[(size_t)(c0 + i) * rows + r0 + tx] = __float2bfloat16(tile[tx][i]);
    }
}

// g_lora: 2-phase BK=64 core (linear inputs). w1T rows 160..255 are zero-padded
// by prep, so the full 128-wide n-tile at n0=128 is safe; epi guards n<160.
__global__ __launch_bounds__(256) void g_lora(const bf16* __restrict__ xxx,
                                              const bf16* __restrict__ w1T,
                                              bf16* __restrict__ L)
{
    __shared__ __align__(16) short lds[32768];
    int m0 = blockIdx.x * 128, n0 = blockIdx.y * 128;
    gemm128L(lds, lds + 16384, xxx, CC, w1T, CC, CC / 64, m0, n0,
             [&](int m, int n, float v) {
                 if (n < 160) L[(size_t)m * 160 + n] = __float2bfloat16(tanhf(v));
             });
}

// ---------------------------------------------------------------------------
// g_xvar v2: per f, 16-MFMA GEMM (K=32) -> acc staged as F32 into LDS E
// (bit-identical arithmetic) -> coalesced readout: 16-B vector xb/xxb loads,
// f32x4 E reads, kg-major 16-B contiguous stores into the blk xvars image
// (1-KB runs). Replaces 960 scalar memory ops/thread with ~120 vector ops.
// LDS = E[128][132] f32 = 66 KB (gemm As/Bs overlay the front, time-sliced).
// ---------------------------------------------------------------------------
__global__ __launch_bounds__(256) void g_xvar(const bf16* __restrict__ L,
                                              const bf16* __restrict__ w2T,
                                              const float* __restrict__ maas,
                                              const bf16* __restrict__ xb,
                                              const bf16* __restrict__ xxb,
                                              bf16* __restrict__ xvars)
{
    __shared__ __align__(16) char smem[128 * 132 * 4];   // 67584 B
    short* As = (short*)smem;            // 4096 shorts (overlay)
    short* Bs = (short*)smem + 4096;     // 4096 shorts (overlay)
    float* E  = (float*)smem;            // [128][132] f32
    const int tid = threadIdx.x;
    const int l = tid & 63, wv = tid >> 6;
    const int wm = wv >> 1, wn = wv & 1;
    const int q = l >> 4, lr = l & 15;
    const int row = tid & 127, kg1 = tid >> 7;
    const int m0 = blockIdx.x * 128, n0 = blockIdx.y * 128;
    const size_t tb0 = ((size_t)(m0 >> 8) * 16 + (n0 >> 6)) * 16384;
    const int mbase = m0 & 255;          // 0 or 128

    for (int f = 0; f < 5; ++f) {
        const bf16* A  = L + f * 32;
        const bf16* Bt = w2T + (size_t)f * CC * 32;
        const float* maa = maas + (size_t)f * CC;
        bf16* out = xvars + (size_t)f * BT * CC;

        __syncthreads();                 // prior f's E readout complete
        const bf16* ga = A  + (size_t)(m0 + row) * 160 + kg1 * 8;
        const bf16* gb = Bt + (size_t)(n0 + row) * 32 + kg1 * 8;
        GLD(ga,      As + tid * 8);
        GLD(ga + 16, As + (tid + 256) * 8);
        GLD(gb,      Bs + tid * 8);
        GLD(gb + 16, Bs + (tid + 256) * 8);
        __syncthreads();                 // staged (vmcnt drained by barrier)
        f32x4 acc[4][4] = {};
        {
            bf16x8 af[4], bfb[4];
#pragma unroll
            for (int mt = 0; mt < 4; ++mt)
                af[mt] = *(const bf16x8*)(As + (q * 128 + wm * 64 + mt * 16 + lr) * 8);
#pragma unroll
            for (int nt = 0; nt < 4; ++nt)
                bfb[nt] = *(const bf16x8*)(Bs + (q * 128 + wn * 64 + nt * 16 + lr) * 8);
#pragma unroll
            for (int mt = 0; mt < 4; ++mt)
#pragma unroll
                for (int nt = 0; nt < 4; ++nt)
                    acc[mt][nt] = MFMA(af[mt], bfb[nt], acc[mt][nt]);
        }
        __syncthreads();                 // frag reads done -> E may overlay
#pragma unroll
        for (int mt = 0; mt < 4; ++mt)
#pragma unroll
            for (int nt = 0; nt < 4; ++nt)
#pragma unroll
                for (int rr = 0; rr < 4; ++rr)
                    E[(wm * 64 + mt * 16 + q * 4 + rr) * 132
                      + wn * 64 + nt * 16 + lr] = acc[mt][nt][rr];
        __syncthreads();                 // E ready
        // readout: 2048 units of 8 cols; kg-major -> contiguous blk stores
#pragma unroll
        for (int it = 0; it < 8; ++it) {
            int g = it * 256 + tid;
            int kg = g >> 7, r = g & 127;
            const float* Ep = E + r * 132 + kg * 8;
            f32x4 v0 = *(const f32x4*)(Ep);
            f32x4 v1 = *(const f32x4*)(Ep + 4);
            size_t xoff = (size_t)(m0 + r) * CC + n0 + kg * 8;
            bf16x8 xbv  = *(const bf16x8*)(xb + xoff);
            bf16x8 xxbv = *(const bf16x8*)(xxb + xoff);
            const float* mp = maa + n0 + kg * 8;
            f32x4 ma0 = *(const f32x4*)(mp);
            f32x4 ma1 = *(const f32x4*)(mp + 4);
            bf16x8 o8;
#pragma unroll
            for (int e = 0; e < 4; ++e) {
                o8[e]     = f2bs(bs2f(xbv[e])     + bs2f(xxbv[e])     * (ma0[e] + v0[e]));
                o8[e + 4] = f2bs(bs2f(xbv[e + 4]) + bs2f(xxbv[e + 4]) * (ma1[e] + v1[e]));
            }
            size_t dst = tb0 + (size_t)(kg >> 3) * 16384 + (size_t)(kg & 7) * 2048
                       + (size_t)(mbase + r) * 8;
            *(bf16x8*)((short*)out + dst) = o8;
        }
    }
}

// ---------------------------------------------------------------------------
// r/k/v GEMMs on the 256^2 core (blocks 0..383) + gate/decay hidden GEMMs on
// the 256x64 core (blocks 384..447). Logical order: z outer, m middle, n
// FASTEST — consecutive 4 blocks on an XCD share the 512 KB A-panel (L2 hit)
// and the z's whole 2 MB B slice stays L2-resident (R10: FETCH 121->59.5 MB).
// ---------------------------------------------------------------------------
__global__ __launch_bounds__(512) void g_rkv5(const bf16* __restrict__ xvars,
                                              const bf16* __restrict__ WT,
                                              const bf16* __restrict__ w1T2,
                                              bf16* __restrict__ rkv,
                                              bf16* __restrict__ hid)
{
    __shared__ __align__(16) short lds[68608];   // 134 KiB (epi needs 256x268)
    int bid = blockIdx.x;
    if (bid < 384) {
        int swz = (bid & 7) * 48 + (bid >> 3);   // 384 % 8 == 0: bijective
        int z  = swz >> 7;                       // 0=r,1=k,2=v
        int r2 = swz & 127;
        int m0 = (r2 >> 2) * 256;                // 32 m-tiles (middle)
        int n0 = (r2 & 3) * 256;                 // 4 n-tiles (fastest)
        int f = (z == 0) ? 3 : z;                // r<-xr(f3), k<-xk(f1), v<-xv(f2)
        const bf16* A  = xvars + (size_t)f * BT * CC;
        const bf16* Bt = WT + (size_t)z * CC * CC;
        bf16* out = rkv + (size_t)z * BT * CC;
        gemm256(lds, A, Bt, CC / 64, m0, n0, out);
    } else {
        int hb = bid - 384;
        int zz = hb >> 5, mi = hb & 31;          // 0=gate(f4), 1=decay(f0)
        const bf16* A  = xvars + (size_t)(zz == 0 ? 4 : 0) * BT * CC;
        const bf16* Bt = w1T2 + (size_t)zz * 128 * CC;
        bf16* out = hid + (size_t)zz * BT * 64;
        gemmHid(lds, lds + 32768, A, Bt, CC, CC / 64, mi * 256,
                [&](int m, int n, float v) {
                    out[(size_t)m * 64 + n] = __float2bfloat16(tanhf(v));
                });
    }
}

// ---------------------------------------------------------------------------
// Chunk-parallel WKV6, pass 1: grid 2048 = (bh,chunk), 256 thr / 4 waves.
// r/k/v and y in head-blocked [bh][t][64] layout (contiguous tiles).
// y written via LDS-staged coalesced epilogue (VT region reused).
// ---------------------------------------------------------------------------
__global__ __launch_bounds__(256) void k_wkv_p1(const bf16* __restrict__ r,
                                                const bf16* __restrict__ kk,
                                                const bf16* __restrict__ vv,
                                                const bf16* __restrict__ hidW,
                                                const bf16* __restrict__ w2d,
                                                const float* __restrict__ td,
                                                const float* __restrict__ u,
                                                bf16* __restrict__ y,
                                                bf16* __restrict__ RTg,
                                                short* __restrict__ Mg,
                                                float* __restrict__ plg)
{
    constexpr int PW = 65, PB = 72;
    __shared__ __align__(16) char smem[16640 + 3 * 9216 + 768];
    float* LW = (float*)smem;                          // [64][65] fp32 scan
    short* VT = (short*)smem;                          // [64][72] bf16 (overlay)
    short* RT = (short*)(smem + 16640);                // [64][72]
    short* KT = (short*)(smem + 16640 + 9216);         // [64][72]
    short* AT = KT;                                    // overlay after MFMA1
    short* KH = (short*)(smem + 16640 + 2 * 9216);     // [64][72]
    short* HT = KT;                                    // hid_w staging (pre-C)
    short* WD = KH;                                    // w2dec staging (pre-C)
    float* SU = (float*)(smem + 16640 + 3 * 9216);
    float* SD = SU + 64;

    const int tid = threadIdx.x;
    const int lane = tid & 63, wq = tid >> 6;
    const int row = tid >> 2, g = tid & 3, j0 = g * 16;
    const int l15 = lane & 15, q = lane >> 4;
    const int bh = blockIdx.x >> 5, c = blockIdx.x & 31;
    const int b = bh >> 4, h = bh & 15;
    const int t0 = c * 64;
    const int bt0 = b * TT + t0;
    const size_t hbb = (size_t)bh * TT * NN;           // head-blocked base
    const size_t cb = (size_t)blockIdx.x * 4096;       // [bh][c] 64x64 tile base

    if (tid < 64) SU[tid] = u[h * NN + tid];

    // ---- phase A0: stage hid_w tile [64t][64k] and w2dec slice [64ch][64k]
#pragma unroll
    for (int rnd = 0; rnd < 2; ++rnd) {
        int ee = rnd * 256 + tid;
        int rw = ee >> 3, c8 = (ee & 7) * 8;
        *(bf16x8*)(HT + rw * PB + c8) =
            *(const bf16x8*)(hidW + (size_t)(bt0 + rw) * 64 + c8);
        *(bf16x8*)(WD + rw * PB + c8) =
            *(const bf16x8*)(w2d + (size_t)(h * 64 + rw) * 64 + c8);
    }
    // r,k,v loads in flight during the lw MFMA (contiguous head-blocked rows)
    const size_t gb = hbb + (size_t)(t0 + row) * 64 + j0;
    bf16x8 r0 = *(const bf16x8*)(r + gb),  r1 = *(const bf16x8*)(r + gb + 8);
    bf16x8 k0 = *(const bf16x8*)(kk + gb), k1 = *(const bf16x8*)(kk + gb + 8);
    bf16x8 v0 = *(const bf16x8*)(vv + gb), v1 = *(const bf16x8*)(vv + gb + 8);
    float tdv[4];
#pragma unroll
    for (int ct = 0; ct < 4; ++ct) tdv[ct] = td[h * 64 + ct * 16 + l15];
    __syncthreads();
    // ---- phase A1: lw tile = hid_w @ w2dec^T ; lw = -exp(td + .)
    {
        bf16x8 aH0 = *(const bf16x8*)(HT + (wq * 16 + l15) * PB + q * 8);
        bf16x8 aH1 = *(const bf16x8*)(HT + (wq * 16 + l15) * PB + q * 8 + 32);
        f32x4 lwa[4] = {};
#pragma unroll
        for (int ct = 0; ct < 4; ++ct) {
            bf16x8 bW0 = *(const bf16x8*)(WD + (ct * 16 + l15) * PB + q * 8);
            bf16x8 bW1 = *(const bf16x8*)(WD + (ct * 16 + l15) * PB + q * 8 + 32);
            lwa[ct] = MFMA(aH0, bW0, lwa[ct]);
            lwa[ct] = MFMA(aH1, bW1, lwa[ct]);
        }
#pragma unroll
        for (int ct = 0; ct < 4; ++ct)
#pragma unroll
            for (int rr = 0; rr < 4; ++rr) {
                int t = wq * 16 + q * 4 + rr, j = ct * 16 + l15;
                LW[t * PW + j] = -expf(tdv[ct] + lwa[ct][rr]);
            }
    }
    __syncthreads();   // LW ready for scan; HT/WD reads done (phase C reuses)
    // ---- phase B: inclusive prefix-sum over t (lane=t), per channel j
    for (int jj = 0; jj < 16; ++jj) {
        int j = wq * 16 + jj;
        float xv = LW[lane * PW + j];
#pragma unroll
        for (int d = 1; d < 64; d <<= 1) {
            float t2 = __shfl_up(xv, d);
            if (lane >= d) xv += t2;
        }
        LW[lane * PW + j] = xv;
    }
    __syncthreads();
    // ---- phase C: build RT, KT, KH, diag, pl
    float rF[16], kF[16];
#pragma unroll
    for (int c2 = 0; c2 < 8; ++c2) {
        rF[c2] = bs2f(r0[c2]); rF[8 + c2] = bs2f(r1[c2]);
        kF[c2] = bs2f(k0[c2]); kF[8 + c2] = bs2f(k1[c2]);
    }
    float cwp[16], cwm[16], cwL[16];
#pragma unroll
    for (int c2 = 0; c2 < 16; ++c2) {
        cwp[c2] = LW[row * PW + j0 + c2];
        cwm[c2] = row ? LW[(row - 1) * PW + j0 + c2] : 0.f;
        cwL[c2] = LW[63 * PW + j0 + c2];
    }
    bf16x8 w0, w1;
#pragma unroll
    for (int c2 = 0; c2 < 8; ++c2) {
        w0[c2] = f2bs(rF[c2] * expf(cwm[c2]));
        w1[c2] = f2bs(rF[8 + c2] * expf(cwm[8 + c2]));
    }
    *(bf16x8*)(RT + row * PB + j0)     = w0;
    *(bf16x8*)(RT + row * PB + j0 + 8) = w1;
    *(bf16x8*)((short*)RTg + cb + row * 64 + j0)     = w0;   // persist for p3
    *(bf16x8*)((short*)RTg + cb + row * 64 + j0 + 8) = w1;
#pragma unroll
    for (int c2 = 0; c2 < 8; ++c2) {
        w0[c2] = f2bs(kF[c2] * expf(-cwp[c2]));
        w1[c2] = f2bs(kF[8 + c2] * expf(-cwp[8 + c2]));
    }
    *(bf16x8*)(KT + row * PB + j0)     = w0;
    *(bf16x8*)(KT + row * PB + j0 + 8) = w1;
#pragma unroll
    for (int c2 = 0; c2 < 16; ++c2)
        KH[(j0 + c2) * PB + row] = f2bs(kF[c2] * expf(cwL[c2] - cwp[c2]));
    if (tid < 64) plg[(size_t)blockIdx.x * 64 + tid] = expf(LW[63 * PW + tid]);
    float dpart = 0.f;
#pragma unroll
    for (int c2 = 0; c2 < 16; ++c2)
        dpart = fmaf(rF[c2] * kF[c2], SU[j0 + c2], dpart);
    dpart += __shfl_xor(dpart, 1);
    dpart += __shfl_xor(dpart, 2);
    if (g == 0) SD[row] = dpart;
    __syncthreads();
    // ---- phase D: VT writes (into dead LW region) + MFMA1 A = RT.KT^T
#pragma unroll
    for (int c2 = 0; c2 < 8; ++c2) {
        VT[(j0 + c2) * PB + row]     = v0[c2];
        VT[(j0 + 8 + c2) * PB + row] = v1[c2];
    }
    bf16x8 aF0 = *(const bf16x8*)(RT + (wq * 16 + l15) * PB + q * 8);
    bf16x8 aF1 = *(const bf16x8*)(RT + (wq * 16 + l15) * PB + q * 8 + 32);
    f32x4 Am[4] = {};
#pragma unroll
    for (int ct = 0; ct < 4; ++ct) {
        bf16x8 bF0 = *(const bf16x8*)(KT + (ct * 16 + l15) * PB + q * 8);
        bf16x8 bF1 = *(const bf16x8*)(KT + (ct * 16 + l15) * PB + q * 8 + 32);
        Am[ct] = MFMA(aF0, bF0, Am[ct]);
        Am[ct] = MFMA(aF1, bF1, Am[ct]);
    }
    __syncthreads();                 // KT reads done -> AT may overlay
#pragma unroll
    for (int ct = 0; ct < 4; ++ct)
#pragma unroll
        for (int rr = 0; rr < 4; ++rr) {
            int s = wq * 16 + q * 4 + rr, p = ct * 16 + l15;
            float vA = Am[ct][rr];
            vA = (p > s) ? 0.f : (p == s ? SD[s] : vA);
            AT[s * PB + p] = f2bs(vA);
        }
    __syncthreads();
    // ---- phase E: Y_local = A.V ; M = VT.KH^T
    f32x4 Y[4] = {}, M[4] = {};
    bf16x8 aA0 = *(const bf16x8*)(AT + (wq * 16 + l15) * PB + q * 8);
    bf16x8 aA1 = *(const bf16x8*)(AT + (wq * 16 + l15) * PB + q * 8 + 32);
    bf16x8 aV0 = *(const bf16x8*)(VT + (wq * 16 + l15) * PB + q * 8);
    bf16x8 aV1 = *(const bf16x8*)(VT + (wq * 16 + l15) * PB + q * 8 + 32);
#pragma unroll
    for (int ct = 0; ct < 4; ++ct) {
        bf16x8 bV0 = *(const bf16x8*)(VT + (ct * 16 + l15) * PB + q * 8);
        bf16x8 bV1 = *(const bf16x8*)(VT + (ct * 16 + l15) * PB + q * 8 + 32);
        Y[ct] = MFMA(aA0, bV0, Y[ct]);
        Y[ct] = MFMA(aA1, bV1, Y[ct]);
        bf16x8 bK0 = *(const bf16x8*)(KH + (ct * 16 + l15) * PB + q * 8);
        bf16x8 bK1 = *(const bf16x8*)(KH + (ct * 16 + l15) * PB + q * 8 + 32);
        M[ct] = MFMA(aV0, bK0, M[ct]);
        M[ct] = MFMA(aV1, bK1, M[ct]);
    }
    __syncthreads();                 // all VT reads done -> Y may overlay VT
#pragma unroll
    for (int ct = 0; ct < 4; ++ct)
#pragma unroll
        for (int rr = 0; rr < 4; ++rr) {
            int s = wq * 16 + q * 4 + rr;
            VT[s * PB + ct * 16 + l15] = f2bs(Y[ct][rr]);   // stage Y
            Mg[cb + (size_t)s * 64 + ct * 16 + l15] = f2bs(M[ct][rr]);
        }
    __syncthreads();
    // coalesced y write: 2 iters x 256 thr x 16 B contiguous hb stores
#pragma unroll
    for (int it = 0; it < 2; ++it) {
        int gidx = it * 256 + tid;           // 512 units of 16 B
        int rY = gidx >> 3, cB = (gidx & 7) * 8;
        *(bf16x8*)((short*)y + hbb + (size_t)(t0 + rY) * 64 + cB) =
            *(const bf16x8*)(VT + rY * PB + cB);
    }
}

// ---------------------------------------------------------------------------
// Pass 2: sequential scan over 32 chunks, elementwise on S[i][j] per (b,h).
// ---------------------------------------------------------------------------
__global__ __launch_bounds__(256) void k_wkv_p2(const short* __restrict__ Mg,
                                                const float* __restrict__ plg,
                                                bf16* __restrict__ Sg)
{
    int bh = blockIdx.x >> 4, part = blockIdx.x & 15;
    int i = part * 4 + (threadIdx.x >> 6), j = threadIdx.x & 63;
    float S = 0.f;
    size_t eb = (size_t)bh * 32 * 4096 + (size_t)i * 64 + j;
    size_t pb = (size_t)bh * 32 * 64 + j;
    for (int c = 0; c < 32; ++c) {
        Sg[eb + (size_t)c * 4096] = __float2bfloat16(S);
        S = plg[pb + (size_t)c * 64] * S + bs2f(Mg[eb + (size_t)c * 4096]);
    }
}

// ---------------------------------------------------------------------------
// Pass 3: gate tile G = hid_g @ gate_w2^T (MFMA, frag-aligned with Y);
// Y = Y_local + RT.S_in (MFMA); fused groupnorm-over-head * G -> A2.
// y read head-blocked; A2 written blk128 via LDS-staged coalesced epilogue.
// ---------------------------------------------------------------------------
__global__ __launch_bounds__(256) void k_wkv_p3(const bf16* __restrict__ RTg,
                                                const bf16* __restrict__ Sg,
                                                const bf16* __restrict__ y,
                                                const bf16* __restrict__ hidG,
                                                const bf16* __restrict__ w2g,
                                                const float* __restrict__ ln_g,
                                                const float* __restrict__ ln_b,
                                                bf16* __restrict__ A2)
{
    constexpr int PB = 72;
    __shared__ __align__(16) short BufA[64 * PB], BufB[64 * PB];
    const int tid = threadIdx.x;
    const int lane = tid & 63, wq = tid >> 6;
    const int l15 = lane & 15, q = lane >> 4;
    const int bh = blockIdx.x >> 5, c = blockIdx.x & 31;
    const int b = bh >> 4, h = bh & 15;
    const int t0 = c * 64;
    const int bt0 = b * TT + t0;
    const size_t hbb = (size_t)bh * TT * NN;
    const size_t cb = (size_t)blockIdx.x * 4096;

    // ---- stage hid_g tile + gate_w2 slice; compute G frags
#pragma unroll
    for (int rnd = 0; rnd < 2; ++rnd) {
        int ee = rnd * 256 + tid;
        int rw = ee >> 3, c8 = (ee & 7) * 8;
        *(bf16x8*)(BufA + rw * PB + c8) =
            *(const bf16x8*)(hidG + (size_t)(bt0 + rw) * 64 + c8);
        *(bf16x8*)(BufB + rw * PB + c8) =
            *(const bf16x8*)(w2g + (size_t)(h * 64 + rw) * 64 + c8);
    }
    __syncthreads();
    f32x4 G[4] = {};
    {
        bf16x8 aH0 = *(const bf16x8*)(BufA + (wq * 16 + l15) * PB + q * 8);
        bf16x8 aH1 = *(const bf16x8*)(BufA + (wq * 16 + l15) * PB + q * 8 + 32);
#pragma unroll
        for (int ct = 0; ct < 4; ++ct) {
            bf16x8 bW0 = *(const bf16x8*)(BufB + (ct * 16 + l15) * PB + q * 8);
            bf16x8 bW1 = *(const bf16x8*)(BufB + (ct * 16 + l15) * PB + q * 8 + 32);
            G[ct] = MFMA(aH0, bW0, G[ct]);
            G[ct] = MFMA(aH1, bW1, G[ct]);
        }
    }
    __syncthreads();
    // ---- stage RT + S_in
#pragma unroll
    for (int rnd = 0; rnd < 2; ++rnd) {
        int ee = rnd * 256 + tid;
        int rw = ee >> 3, c8 = (ee & 7) * 8;
        *(bf16x8*)(BufA + rw * PB + c8) =
            *(const bf16x8*)((const short*)RTg + cb + rw * 64 + c8);
        *(bf16x8*)(BufB + rw * PB + c8) =
            *(const bf16x8*)((const short*)Sg + cb + rw * 64 + c8);
    }
    __syncthreads();

    // preload Y_local into C frags, accumulate cross term on top
    f32x4 Yc[4];
#pragma unroll
    for (int ct = 0; ct < 4; ++ct)
#pragma unroll
        for (int rr = 0; rr < 4; ++rr) {
            int s = wq * 16 + q * 4 + rr;
            Yc[ct][rr] = __bfloat162float(
                y[hbb + (size_t)(t0 + s) * 64 + ct * 16 + l15]);
        }
    bf16x8 aF0 = *(const bf16x8*)(BufA + (wq * 16 + l15) * PB + q * 8);
    bf16x8 aF1 = *(const bf16x8*)(BufA + (wq * 16 + l15) * PB + q * 8 + 32);
#pragma unroll
    for (int ct = 0; ct < 4; ++ct) {
        bf16x8 bS0 = *(const bf16x8*)(BufB + (ct * 16 + l15) * PB + q * 8);
        bf16x8 bS1 = *(const bf16x8*)(BufB + (ct * 16 + l15) * PB + q * 8 + 32);
        Yc[ct] = MFMA(aF0, bS0, Yc[ct]);
        Yc[ct] = MFMA(aF1, bS1, Yc[ct]);
    }
    __syncthreads();                 // BufA/BufB reads done -> stage A2 in BufA
    // groupnorm over the 64 head channels (cols = ct*16+l15) per row s, * G
#pragma unroll
    for (int rr = 0; rr < 4; ++rr) {
        float s1 = 0.f, s2 = 0.f;
#pragma unroll
        for (int ct = 0; ct < 4; ++ct) {
            float vA = Yc[ct][rr];
            s1 += vA; s2 += vA * vA;
        }
#pragma unroll
        for (int o = 1; o < 16; o <<= 1) {
            s1 += __shfl_xor(s1, o);
            s2 += __shfl_xor(s2, o);
        }
        float mu  = s1 * (1.f / 64.f);
        float var = s2 * (1.f / 64.f) - mu * mu;
        float rstd = rsqrtf(var + 6.4e-4f);
        int s = wq * 16 + q * 4 + rr;
#pragma unroll
        for (int ct = 0; ct < 4; ++ct) {
            int ch = h * NN + ct * 16 + l15;
            float yn = (Yc[ct][rr] - mu) * rstd;
            float outv = (yn * ln_g[ch] + ln_b[ch]) * G[ct][rr];
            BufA[s * PB + ct * 16 + l15] = f2bs(outv);       // stage A2 tile
        }
    }
    __syncthreads();
    // coalesced A2 write into blk128 image: rows bt0..+63, ktile h.
    // Per kg, 64 rows x 8 shorts contiguous; lanes sweep rows -> 1 KB runs.
    {
        const size_t tb = ((size_t)((bt0) >> 7) * 16 + h) * 8192;
        const int rowbase = bt0 & 127;               // 0 or 64
#pragma unroll
        for (int it = 0; it < 2; ++it) {
            int gidx = it * 256 + tid;               // 512 units of 16 B
            int kg = gidx >> 6, rA = gidx & 63;
            *(bf16x8*)((short*)A2 + tb + kg * 1024 + (size_t)(rowbase + rA) * 8) =
                *(const bf16x8*)(BufA + rA * PB + kg * 8);
        }
    }
}

// g_out: 512 blocks, XCD swizzle (R9 orientation — best-total config): each
// chunk of 64 logical blocks shares one WoT n-panel. 512 % 8 == 0: bijective.
__global__ __launch_bounds__(256) void g_out(const bf16* __restrict__ A2,
                                             const bf16* __restrict__ WoT,
                                             float* __restrict__ out)
{
    __shared__ __align__(16) short lds[32768];
    int bid = blockIdx.x;
    int swz = (bid & 7) * 64 + (bid >> 3);
    int m0 = (swz & 63) * 128, n0 = (swz >> 6) * 128;
    gemm128b(lds, lds + 16384, A2, WoT, CC / 64, m0, n0,
             [&](int m, int n, float v) { out[(size_t)m * CC + n] = v; });
}

// ---------------------------------------------------------------------------
extern "C" void kernel_launch(void* const* d_in, const int* in_sizes, int n_in,
                              void* d_out, int out_size, void* d_ws, size_t ws_size,
                              hipStream_t stream)
{
    const float* x        = (const float*)d_in[0];
    const float* maa_x    = (const float*)d_in[1];
    const float* maa_w    = (const float*)d_in[2];
    const float* maa_k    = (const float*)d_in[3];
    const float* maa_v    = (const float*)d_in[4];
    const float* maa_r    = (const float*)d_in[5];
    const float* maa_g    = (const float*)d_in[6];
    const float* maa_w1   = (const float*)d_in[7];
    const float* maa_w2   = (const float*)d_in[8];
    const float* Wr       = (const float*)d_in[9];
    const float* Wk       = (const float*)d_in[10];
    const float* Wv       = (const float*)d_in[11];
    const float* Wo       = (const float*)d_in[12];
    const float* gate_w1  = (const float*)d_in[13];
    const float* gate_w2  = (const float*)d_in[14];
    const float* time_dec = (const float*)d_in[15];
    const float* decay_w1 = (const float*)d_in[16];
    const float* decay_w2 = (const float*)d_in[17];
    const float* u        = (const float*)d_in[18];
    const float* ln_g     = (const float*)d_in[19];
    const float* ln_b     = (const float*)d_in[20];

    // --- workspace layout with lifetime reuse ---
    size_t off = 0;
    auto alloc = [&](size_t bytes) {
        off = (off + 255) & ~(size_t)255;
        void* p = (char*)d_ws + off;
        off += bytes;
        return p;
    };
    bf16*  WT3   = (bf16*) alloc(3ull * CC * CC * 2);       // WrT,WkT,WvT (blk256)
    bf16*  WoT   = (bf16*) alloc((size_t)CC * CC * 2);      // blk128
    bf16*  w1T   = (bf16*) alloc(256ull * CC * 2);          // maa_w1^T padded
    bf16*  w1T2  = (bf16*) alloc(2ull * 128 * CC * 2);      // gate_w1^T, decay_w1^T
    bf16*  w2T2  = (bf16*) alloc(2ull * CC * 64 * 2);       // gate_w2^T, decay_w2^T
    bf16*  w2T5  = (bf16*) alloc(5ull * CC * 32 * 2);       // maa_w2[f]^T
    float* maas  = (float*)alloc(5ull * CC * 4);
    // bufA 16 MB: xxx (dead after g_lora) -> A2 blk128 (written by p3)
    char* bufA = (char*)alloc((size_t)BT * CC * 2);
    bf16* xxxbf = (bf16*)bufA;
    bf16* A2    = (bf16*)bufA;
    // bufB 2.56 MB: lora (dead after g_xvar) -> hid (2 MB, lives through p3)
    char* bufB = (char*)alloc((size_t)BT * 160 * 2);
    bf16* Lbf  = (bf16*)bufB;
    bf16* hid  = (bf16*)bufB;
    // bufC 80 MB: xvars blocked (dead after g_rkv5) -> ybuf bf16(16M) | RTg(16.8M)
    char* bufC = (char*)alloc(5ull * BT * CC * 2);
    bf16*  xvars = (bf16*)bufC;
    bf16*  ybuf  = (bf16*)bufC;
    bf16*  RTg   = (bf16*)(bufC + (size_t)BT * CC * 2);
    // bufD 48 MB: r,k,v bf16 (dead after p1) -> S_in bf16 (16.8M, by p2)
    bf16*  rkv  = (bf16*)alloc(3ull * BT * CC * 2);
    bf16*  Sg   = rkv;
    // xb/xxb bf16 packs (16 MB each), Mg bf16 (16.8 MB), pl fp32 (0.5 MB)
    bf16*  xb   = (bf16*) alloc((size_t)BT * CC * 2);
    bf16*  xxb  = (bf16*) alloc((size_t)BT * CC * 2);
    short* Mg   = (short*)alloc(64ull * 32 * 4096 * 2);
    float* plg  = (float*)alloc(64ull * 32 * 64 * 4);

    // --- single fused prep launch (weights + xxx/xb/xxb) ---
    k_prep_all<<<dim3(13092), 256, 0, stream>>>(
        Wr, Wk, Wv, Wo, maa_w1, gate_w1, decay_w1, gate_w2, decay_w2, maa_w2,
        maa_w, maa_k, maa_v, maa_r, maa_g, x, maa_x,
        WT3, WoT, w1T, w1T2, w2T2, w2T5, maas, xxxbf, xb, xxb);

    // --- forward pipeline ---
    g_lora<<<dim3(64, 2), 256, 0, stream>>>(xxxbf, w1T, Lbf);
    g_xvar<<<dim3(64, 8), 256, 0, stream>>>(Lbf, w2T5, maas, xb, xxb, xvars);
    g_rkv5<<<dim3(448), 512, 0, stream>>>(xvars, WT3, w1T2, rkv, hid);
    k_wkv_p1<<<dim3(2048), 256, 0, stream>>>(rkv, rkv + (size_t)BT * CC,
                                             rkv + 2ull * BT * CC,
                                             hid + (size_t)BT * 64,   // hid_w
                                             w2T2 + CC * 64,          // decay_w2^T
                                             time_dec, u, ybuf, RTg, Mg, plg);
    k_wkv_p2<<<dim3(1024), 256, 0, stream>>>(Mg, plg, Sg);
    k_wkv_p3<<<dim3(2048), 256, 0, stream>>>(RTg, Sg, ybuf,
                                             hid,                     // hid_g
                                             w2T2,                    // gate_w2^T
                                             ln_g, ln_b, A2);
    g_out<<<dim3(512), 256, 0, stream>>>(A2, WoT, (float*)d_out);
}